// Round 14
// baseline (318.249 us; speedup 1.0000x reference)
//
#include <hip/hip_runtime.h>

#define N_NODES   100000
#define N_EDGES   1600000
#define D         64
#define N_TARGETS 100
#define N_GRAPHS  512
#define NBUCK     391     // ceil(N_NODES / 256): bucket b = dst >> 8
#define EPB       4096    // edges per block in pass A
#define BCAP      6144    // bucket slab capacity (Poisson(4096) + 32 sigma)
#define MM_NPW    16      // nodes per wave in k_mm
#define NPN       8       // nodes per wave in pull kernels (R13: 4 -> 8)

typedef _Float16 half4 __attribute__((ext_vector_type(4)));
typedef _Float16 half8 __attribute__((ext_vector_type(8)));
typedef __fp16   hf2   __attribute__((ext_vector_type(2)));   // builtin-compatible
typedef __fp16   hf8   __attribute__((ext_vector_type(8)));

#if defined(__has_builtin)
#if __has_builtin(__builtin_amdgcn_fdot2)
#define USE_DOT2 1
#endif
#endif

// ---- fused setup: block 0 -> prep W2, block 1 -> prep W3, rest -> zeroing ----
__device__ __forceinline__ void prepW_dev(const float* __restrict__ W,
                                          _Float16* __restrict__ out, int t) {
#pragma unroll
    for (int it = 0; it < 2; ++it) {
        int idx = t + it * 256;        // 512 (m, c) chunks
        int m = idx >> 3, c = idx & 7;
        half8 hv;
#pragma unroll
        for (int tt = 0; tt < 8; ++tt)
            hv[tt] = (_Float16)W[(8 * c + tt) * 64 + m];
        *(half8*)&out[m * 64 + ((c ^ (m & 7)) * 8)] = hv;
    }
}

__global__ void k_setup(const float* __restrict__ W2, const float* __restrict__ W3,
                        _Float16* __restrict__ WhA, _Float16* __restrict__ WhB,
                        int* __restrict__ gcur, float* __restrict__ poolz) {
    int blk = blockIdx.x;
    int t = threadIdx.x;
    if (blk == 0) { prepW_dev(W2, WhA, t); return; }
    if (blk == 1) { prepW_dev(W3, WhB, t); return; }
    int i = (blk - 2) * 256 + t;
    if (i < NBUCK) gcur[i] = 0;
    if (i < N_GRAPHS * D + N_GRAPHS) poolz[i] = 0.0f;
}

// ---- pass A: bucket edges by dst>>8 into fixed-capacity slabs ----
__global__ void __launch_bounds__(256)
k_binA(const int* __restrict__ src, const int* __restrict__ dst,
       int* __restrict__ gcur, unsigned long long* __restrict__ staged) {
    __shared__ int hist[NBUCK];
    __shared__ int boff[NBUCK];
    int tid = threadIdx.x;
    for (int i = tid; i < NBUCK; i += 256) hist[i] = 0;
    __syncthreads();

    int e0 = blockIdx.x * EPB;
    int s_[16], d_[16], r_[16];
#pragma unroll
    for (int k = 0; k < 16; ++k) {
        int e = e0 + k * 256 + tid;
        if (e < N_EDGES) {
            s_[k] = src[e];
            d_[k] = dst[e];
            r_[k] = atomicAdd(&hist[d_[k] >> 8], 1);
        } else {
            d_[k] = -1;
        }
    }
    __syncthreads();
    for (int b = tid; b < NBUCK; b += 256) {
        int h = hist[b];
        boff[b] = (h > 0) ? atomicAdd(&gcur[b], h) : 0;
    }
    __syncthreads();
#pragma unroll
    for (int k = 0; k < 16; ++k) {
        if (d_[k] >= 0) {
            int b = d_[k] >> 8;
            staged[(size_t)b * BCAP + boff[b] + r_[k]] =
                ((unsigned long long)(unsigned)d_[k] << 32) | (unsigned)s_[k];
        }
    }
}

// ---- scan bucket totals -> bucket edge-space starts ----
__global__ void k_scanB(const int* __restrict__ gcur, int* __restrict__ bstart) {
    __shared__ int s[512];
    int t = threadIdx.x;
    int v = (t < NBUCK) ? gcur[t] : 0;
    s[t] = v;
    __syncthreads();
    for (int off = 1; off < 512; off <<= 1) {
        int x = (t >= off) ? s[t - off] : 0;
        __syncthreads();
        s[t] += x;
        __syncthreads();
    }
    if (t < NBUCK) bstart[t] = s[t] - v;
    if (t == 0) bstart[NBUCK] = N_EDGES;
}

// ---- pass B: one block per bucket; LDS degree count + scan + place ----
__global__ void __launch_bounds__(256)
k_binB(const unsigned long long* __restrict__ staged, const int* __restrict__ gcur,
       const int* __restrict__ bstart, int* __restrict__ esrc,
       int* __restrict__ base, float* __restrict__ dinv) {
    __shared__ int s[256];
    __shared__ int lbase[256];
    __shared__ int cur[256];
    int b = blockIdx.x;
    int t = threadIdx.x;
    int n0 = b << 8;
    int Eb = gcur[b];
    int Sb = bstart[b];
    const unsigned long long* sl = staged + (size_t)b * BCAP;

    cur[t] = 0;
    __syncthreads();
    for (int k = t; k < Eb; k += 256) {
        int dl = ((int)(sl[k] >> 32)) & 255;
        atomicAdd(&cur[dl], 1);
    }
    __syncthreads();
    int v = cur[t];
    s[t] = v;
    __syncthreads();
    for (int off = 1; off < 256; off <<= 1) {
        int x = (t >= off) ? s[t - off] : 0;
        __syncthreads();
        s[t] += x;
        __syncthreads();
    }
    lbase[t] = s[t] - v;
    int gi = n0 + t;
    if (gi < N_NODES) {
        base[gi] = Sb + (s[t] - v);
        dinv[gi] = rsqrtf((float)v + 1.0f);   // +1 self-loop
    }
    if (b == 0 && t == 0) base[N_NODES] = N_EDGES;
    cur[t] = 0;
    __syncthreads();
    for (int k = t; k < Eb; k += 256) {
        unsigned long long pd = sl[k];
        int dl = ((int)(pd >> 32)) & 255;
        int pos = Sb + lbase[dl] + atomicAdd(&cur[dl], 1);
        esrc[pos] = (int)(pd & 0xffffffffu);
    }
}

// ------ matmul (layer 1): per-lane-feature, W1 column in registers ----------
__global__ void __launch_bounds__(256)
k_mm(const float* __restrict__ X, const float* __restrict__ W,
     const float* __restrict__ dinv, _Float16* __restrict__ Y16) {
    __shared__ float W1L[D * D];   // 16 KB raw [k][m]
    __shared__ float aSh[4][D];    // per-wave X row
    int tid = threadIdx.x;
#pragma unroll
    for (int it = 0; it < 4; ++it) {
        int idx = (tid + it * 256) * 4;
        *(float4*)&W1L[idx] = *(const float4*)(W + idx);
    }
    __syncthreads();

    int wv = tid >> 6, lane = tid & 63;
    float wreg[D];   // W1[k][lane] for all k
#pragma unroll
    for (int k = 0; k < D; ++k)
        wreg[k] = W1L[k * D + lane];

    int i0 = (blockIdx.x * 4 + wv) * MM_NPW;
    if (i0 >= N_NODES) return;
    int iEnd = i0 + MM_NPW; if (iEnd > N_NODES) iEnd = N_NODES;

    float xv = X[(size_t)i0 * D + lane];
    for (int i = i0; i < iEnd; ++i) {
        int inext = (i + 1 < N_NODES) ? (i + 1) : i;
        float xnext = X[(size_t)inext * D + lane];

        aSh[wv][lane] = xv;
        asm volatile("s_waitcnt lgkmcnt(0)" ::: "memory");

        float ac0 = 0.f, ac1 = 0.f, ac2 = 0.f, ac3 = 0.f;
#pragma unroll
        for (int c = 0; c < 16; ++c) {
            float4 a4 = *(const float4*)&aSh[wv][c * 4];
            ac0 = fmaf(a4.x, wreg[4 * c + 0], ac0);
            ac1 = fmaf(a4.y, wreg[4 * c + 1], ac1);
            ac2 = fmaf(a4.z, wreg[4 * c + 2], ac2);
            ac3 = fmaf(a4.w, wreg[4 * c + 3], ac3);
        }
        float acc = (ac0 + ac1) + (ac2 + ac3);
        Y16[(size_t)i * D + lane] = (_Float16)(acc * dinv[i]);
        xv = xnext;
    }
}

// ---- fused pull + matmul: R12 structure, NPN=8 (prologue amortized 2x).
// No setup-prefetch (R11: VGPR 36->60, occ 57->37%, +19us — rejected).
__global__ void __launch_bounds__(256)
k_pullmm(const _Float16* __restrict__ H, const int* __restrict__ esrc,
         const int* __restrict__ base, const float* __restrict__ dinv,
         const float* __restrict__ b_in, const _Float16* __restrict__ Whg,
         _Float16* __restrict__ Hout) {
    __shared__ _Float16 WhL[D * D];        // 8KB swizzled Wt
    __shared__ float    red[4][8][D + 4];  // 8.5KB transpose-reduce tile
    __shared__ _Float16 aSh[4][D];         // 512B activation rows
    {
#pragma unroll
        for (int it = 0; it < 2; ++it) {
            int t = threadIdx.x + it * 256;
            *(half8*)&WhL[t * 8] = *(const half8*)&Whg[t * 8];
        }
    }
    __syncthreads();

    int wv   = threadIdx.x >> 6;
    int lane = threadIdx.x & 63;
    int g = lane >> 3, l = lane & 7;
    float bias = b_in[lane];
    int i0 = (blockIdx.x * 4 + wv) * NPN;

    for (int n = 0; n < NPN; ++n) {
        int i = i0 + n;
        int s0 = base[i], s1 = base[i + 1];

        float acc[8] = {0.f, 0.f, 0.f, 0.f, 0.f, 0.f, 0.f, 0.f};
        if (g == 0) {       // self contribution (group 0 only)
            half8 sv = *(const half8*)(H + (size_t)i * D + l * 8);
#pragma unroll
            for (int q = 0; q < 8; ++q) acc[q] = (float)sv[q];
        }

        int p = s0;
        while (p < s1) {
            int cnt = s1 - p;
            if (cnt > 64) cnt = 64;
            int ed = (lane < cnt) ? esrc[p + lane] : 0;
            int j = 0;
            for (; j + 32 <= cnt; j += 32) {
                int e0 = __shfl(ed, j + g, 64);
                int e1 = __shfl(ed, j + 8 + g, 64);
                int e2 = __shfl(ed, j + 16 + g, 64);
                int e3 = __shfl(ed, j + 24 + g, 64);
                half8 v0 = *(const half8*)(H + (size_t)(unsigned)e0 * D + l * 8);
                half8 v1 = *(const half8*)(H + (size_t)(unsigned)e1 * D + l * 8);
                half8 v2 = *(const half8*)(H + (size_t)(unsigned)e2 * D + l * 8);
                half8 v3 = *(const half8*)(H + (size_t)(unsigned)e3 * D + l * 8);
                half8 s01 = v0 + v1;
                half8 s23 = v2 + v3;
#pragma unroll
                for (int q = 0; q < 8; ++q)
                    acc[q] += (float)s01[q] + (float)s23[q];
            }
            for (; j + 16 <= cnt; j += 16) {
                int e0 = __shfl(ed, j + g, 64);
                int e1 = __shfl(ed, j + 8 + g, 64);
                half8 v0 = *(const half8*)(H + (size_t)(unsigned)e0 * D + l * 8);
                half8 v1 = *(const half8*)(H + (size_t)(unsigned)e1 * D + l * 8);
                half8 s01 = v0 + v1;
#pragma unroll
                for (int q = 0; q < 8; ++q) acc[q] += (float)s01[q];
            }
            for (; j + 8 <= cnt; j += 8) {
                int e0 = __shfl(ed, j + g, 64);
                half8 v0 = *(const half8*)(H + (size_t)(unsigned)e0 * D + l * 8);
#pragma unroll
                for (int q = 0; q < 8; ++q) acc[q] += (float)v0[q];
            }
            if (j < cnt) {
                int idx = j + g;
                int e0 = __shfl(ed, idx & 63, 64);
                if (idx < cnt) {
                    half8 v0 = *(const half8*)(H + (size_t)(unsigned)e0 * D + l * 8);
#pragma unroll
                    for (int q = 0; q < 8; ++q) acc[q] += (float)v0[q];
                }
            }
            p += cnt;
        }

        // ---- LDS transpose-reduce (2 independent add chains) ----
        *(float4*)&red[wv][g][l * 8]     = make_float4(acc[0], acc[1], acc[2], acc[3]);
        *(float4*)&red[wv][g][l * 8 + 4] = make_float4(acc[4], acc[5], acc[6], acc[7]);
        asm volatile("s_waitcnt lgkmcnt(0)" ::: "memory");
        float ag0 = 0.f, ag1 = 0.f;
#pragma unroll
        for (int gg = 0; gg < 8; gg += 2) {
            ag0 += red[wv][gg][lane];
            ag1 += red[wv][gg + 1][lane];
        }
        float agg = ag0 + ag1;

        float di = dinv[i];
        float av = fmaxf(fmaf(agg, di, bias), 0.f);
        aSh[wv][lane] = (_Float16)av;
        asm volatile("s_waitcnt lgkmcnt(0)" ::: "memory");

        // ---- dot2 epilogue: 4 independent accumulators (chain 32 -> 8) ----
        float p0 = 0.f, p1 = 0.f, p2 = 0.f, p3 = 0.f;
#pragma unroll
        for (int c = 0; c < 8; ++c) {
            hf8 a8 = *(const hf8*)&aSh[wv][c * 8];                           // broadcast
            hf8 w8 = *(const hf8*)&WhL[lane * 64 + ((c ^ (lane & 7)) * 8)];  // swizzled
#ifdef USE_DOT2
            hf2 a0; a0.x = a8[0]; a0.y = a8[1];
            hf2 a1; a1.x = a8[2]; a1.y = a8[3];
            hf2 a2; a2.x = a8[4]; a2.y = a8[5];
            hf2 a3; a3.x = a8[6]; a3.y = a8[7];
            hf2 w0; w0.x = w8[0]; w0.y = w8[1];
            hf2 w1; w1.x = w8[2]; w1.y = w8[3];
            hf2 w2; w2.x = w8[4]; w2.y = w8[5];
            hf2 w3; w3.x = w8[6]; w3.y = w8[7];
            p0 = __builtin_amdgcn_fdot2(a0, w0, p0, false);
            p1 = __builtin_amdgcn_fdot2(a1, w1, p1, false);
            p2 = __builtin_amdgcn_fdot2(a2, w2, p2, false);
            p3 = __builtin_amdgcn_fdot2(a3, w3, p3, false);
#else
#pragma unroll
            for (int t = 0; t < 8; t += 4) {
                p0 = fmaf((float)a8[t],     (float)w8[t],     p0);
                p1 = fmaf((float)a8[t + 1], (float)w8[t + 1], p1);
                p2 = fmaf((float)a8[t + 2], (float)w8[t + 2], p2);
                p3 = fmaf((float)a8[t + 3], (float)w8[t + 3], p3);
            }
#endif
        }
        float part = (p0 + p1) + (p2 + p3);
        Hout[(size_t)i * D + lane] = (_Float16)(part * di);
    }
}

// ---- final pull (layer 3): R12 structure, NPN=8, AGG16 out ----
__global__ void __launch_bounds__(256)
k_pull(const _Float16* __restrict__ H, const int* __restrict__ esrc,
       const int* __restrict__ base, const float* __restrict__ dinv,
       const float* __restrict__ b, _Float16* __restrict__ AGG16) {
    __shared__ float red[4][8][D + 4];
    int wv   = threadIdx.x >> 6;
    int lane = threadIdx.x & 63;
    int g = lane >> 3, l = lane & 7;
    float bias = b[lane];
    int i0 = (blockIdx.x * 4 + wv) * NPN;

    for (int n = 0; n < NPN; ++n) {
        int i = i0 + n;
        int s0 = base[i], s1 = base[i + 1];

        float acc[8] = {0.f, 0.f, 0.f, 0.f, 0.f, 0.f, 0.f, 0.f};
        if (g == 0) {
            half8 sv = *(const half8*)(H + (size_t)i * D + l * 8);
#pragma unroll
            for (int q = 0; q < 8; ++q) acc[q] = (float)sv[q];
        }

        int p = s0;
        while (p < s1) {
            int cnt = s1 - p;
            if (cnt > 64) cnt = 64;
            int ed = (lane < cnt) ? esrc[p + lane] : 0;
            int j = 0;
            for (; j + 32 <= cnt; j += 32) {
                int e0 = __shfl(ed, j + g, 64);
                int e1 = __shfl(ed, j + 8 + g, 64);
                int e2 = __shfl(ed, j + 16 + g, 64);
                int e3 = __shfl(ed, j + 24 + g, 64);
                half8 v0 = *(const half8*)(H + (size_t)(unsigned)e0 * D + l * 8);
                half8 v1 = *(const half8*)(H + (size_t)(unsigned)e1 * D + l * 8);
                half8 v2 = *(const half8*)(H + (size_t)(unsigned)e2 * D + l * 8);
                half8 v3 = *(const half8*)(H + (size_t)(unsigned)e3 * D + l * 8);
                half8 s01 = v0 + v1;
                half8 s23 = v2 + v3;
#pragma unroll
                for (int q = 0; q < 8; ++q)
                    acc[q] += (float)s01[q] + (float)s23[q];
            }
            for (; j + 16 <= cnt; j += 16) {
                int e0 = __shfl(ed, j + g, 64);
                int e1 = __shfl(ed, j + 8 + g, 64);
                half8 v0 = *(const half8*)(H + (size_t)(unsigned)e0 * D + l * 8);
                half8 v1 = *(const half8*)(H + (size_t)(unsigned)e1 * D + l * 8);
                half8 s01 = v0 + v1;
#pragma unroll
                for (int q = 0; q < 8; ++q) acc[q] += (float)s01[q];
            }
            for (; j + 8 <= cnt; j += 8) {
                int e0 = __shfl(ed, j + g, 64);
                half8 v0 = *(const half8*)(H + (size_t)(unsigned)e0 * D + l * 8);
#pragma unroll
                for (int q = 0; q < 8; ++q) acc[q] += (float)v0[q];
            }
            if (j < cnt) {
                int idx = j + g;
                int e0 = __shfl(ed, idx & 63, 64);
                if (idx < cnt) {
                    half8 v0 = *(const half8*)(H + (size_t)(unsigned)e0 * D + l * 8);
#pragma unroll
                    for (int q = 0; q < 8; ++q) acc[q] += (float)v0[q];
                }
            }
            p += cnt;
        }

        *(float4*)&red[wv][g][l * 8]     = make_float4(acc[0], acc[1], acc[2], acc[3]);
        *(float4*)&red[wv][g][l * 8 + 4] = make_float4(acc[4], acc[5], acc[6], acc[7]);
        asm volatile("s_waitcnt lgkmcnt(0)" ::: "memory");
        float ag0 = 0.f, ag1 = 0.f;
#pragma unroll
        for (int gg = 0; gg < 8; gg += 2) {
            ag0 += red[wv][gg][lane];
            ag1 += red[wv][gg + 1][lane];
        }
        float agg = ag0 + ag1;
        asm volatile("s_waitcnt lgkmcnt(0)" ::: "memory");

        AGG16[(size_t)i * D + lane] = (_Float16)fmaf(agg, dinv[i], bias);
    }
}

// ---- segment-sorted pooling (fp16 in, fp32 accumulate, fused counts) ----
__global__ void __launch_bounds__(256)
k_pool_seg(const _Float16* __restrict__ H16, const int* __restrict__ seg,
           float* __restrict__ pooled, float* __restrict__ counts) {
    int wave = threadIdx.x >> 6;
    int lane = threadIdx.x & 63;
    int n0 = (blockIdx.x * 4 + wave) * 64;
    if (n0 >= N_NODES) return;
    int nEnd = n0 + 64;
    if (nEnd > N_NODES) nEnd = N_NODES;
    int cur = seg[n0];
    float acc = 0.0f;
    int run = 0;
    for (int n = n0; n < nEnd; ++n) {
        int gsg = seg[n];  // wave-uniform
        if (gsg != cur) {
            atomicAdd(&pooled[(size_t)cur * D + lane], acc);
            if (lane == 0) atomicAdd(&counts[cur], (float)run);
            acc = 0.0f; run = 0;
            cur = gsg;
        }
        acc += (float)H16[(size_t)n * D + lane];
        run += 1;
    }
    atomicAdd(&pooled[(size_t)cur * D + lane], acc);
    if (lane == 0) atomicAdd(&counts[cur], (float)run);
}

// ---------------- head ----------------
__global__ void k_out(const float* __restrict__ pooled, const float* __restrict__ counts,
                      const float* __restrict__ Wout, const float* __restrict__ bout,
                      float* __restrict__ out) {
    __shared__ float prow[D];
    int g = blockIdx.x;
    int t = threadIdx.x;
    if (t < D) prow[t] = pooled[(size_t)g * D + t] / fmaxf(counts[g], 1.0f);
    __syncthreads();
    if (t < N_TARGETS) {
        float acc = bout[t];
#pragma unroll
        for (int k = 0; k < D; ++k)
            acc = fmaf(prow[k], Wout[k * N_TARGETS + t], acc);
        out[g * N_TARGETS + t] = acc;
    }
}

// ---------------- driver ----------------

extern "C" void kernel_launch(void* const* d_in, const int* in_sizes, int n_in,
                              void* d_out, int out_size, void* d_ws, size_t ws_size,
                              hipStream_t stream) {
    const float* x    = (const float*)d_in[0];
    const float* W1   = (const float*)d_in[1];
    const float* b1   = (const float*)d_in[2];
    const float* W2   = (const float*)d_in[3];
    const float* b2   = (const float*)d_in[4];
    const float* W3   = (const float*)d_in[5];
    const float* b3   = (const float*)d_in[6];
    const float* Wout = (const float*)d_in[7];
    const float* bout = (const float*)d_in[8];
    const int*   eidx = (const int*)d_in[9];
    const int*   seg  = (const int*)d_in[10];
    const int* src = eidx;
    const int* dst = eidx + N_EDGES;
    float* out = (float*)d_out;

    // workspace layout (~33 MB). staged (19.2 MB) aliases H16A+H16B (dead
    // during CSR build); AGG16 aliases H16B (dead after pullmm#2).
    _Float16* H16A   = (_Float16*)d_ws;                       // 6.4M halfs (12.8MB)
    _Float16* H16B   = H16A + (size_t)N_NODES * D;            // 6.4M halfs
    _Float16* AGG16  = H16B;                                  // alias
    unsigned long long* staged = (unsigned long long*)d_ws;   // alias: 391*6144 pairs
    int*      esrc   = (int*)(H16B + (size_t)N_NODES * D);    // 1.6M
    float*    dinv   = (float*)(esrc + N_EDGES);              // 100k
    int*      base   = (int*)(dinv + N_NODES);                // 100k+1 (+pad)
    float*    pooled = (float*)(base + N_NODES + 4);          // 32768
    float*    counts = pooled + N_GRAPHS * D;                 // 512
    int*      gcur   = (int*)(counts + N_GRAPHS);             // 391 (+pad to 512)
    int*      bstart = gcur + 512;                            // 392 (+pad to 512)
    _Float16* WhA    = (_Float16*)(bstart + 512);             // 4096 halfs (8KB)
    _Float16* WhB    = WhA + 4096;                            // 4096 halfs (8KB)

    const int NB = (N_NODES + 255) / 256;  // 391

    // ---- fused setup: W2/W3 fp16 prep + cursor/pool zeroing (one launch) ----
    k_setup<<<132, 256, 0, stream>>>(W2, W3, WhA, WhB, gcur, pooled);

    // ---- CSR build: slab-bucketed scatter with in-bucket degree counting ----
    k_binA<<<(N_EDGES + EPB - 1) / EPB, 256, 0, stream>>>(src, dst, gcur, staged);
    k_scanB<<<1, 512, 0, stream>>>(gcur, bstart);
    k_binB<<<NBUCK, 256, 0, stream>>>(staged, gcur, bstart, esrc, base, dinv);

    // ---- 3 GCN layers (mm1 separate; mm2/mm3 fused into pulls) ----
    const int MMB = (N_NODES + 4 * MM_NPW - 1) / (4 * MM_NPW);  // 1563
    const int PB  = N_NODES / (4 * NPN);                        // 3125
    k_mm<<<MMB, 256, 0, stream>>>(x, W1, dinv, H16A);
    k_pullmm<<<PB, 256, 0, stream>>>(H16A, esrc, base, dinv, b1, WhA, H16B);
    k_pullmm<<<PB, 256, 0, stream>>>(H16B, esrc, base, dinv, b2, WhB, H16A);
    k_pull<<<PB, 256, 0, stream>>>(H16A, esrc, base, dinv, b3, AGG16);

    // ---- mean pool (sorted-segment, fused counts) + head ----
    k_pool_seg<<<NB, 256, 0, stream>>>(AGG16, seg, pooled, counts);
    k_out<<<N_GRAPHS, 128, 0, stream>>>(pooled, counts, Wout, bout, out);
}

// Round 15
// 309.916 us; speedup vs baseline: 1.0269x; 1.0269x over previous
//
#include <hip/hip_runtime.h>

#define N_NODES   100000
#define N_EDGES   1600000
#define D         64
#define N_TARGETS 100
#define N_GRAPHS  512
#define NBUCK     391     // ceil(N_NODES / 256): bucket b = dst >> 8
#define EPB       16384   // edges per block in pass A (1024 thr x 16)
#define BCAP      6144    // bucket slab capacity (Poisson(4096) + 32 sigma)
#define MM_NPW    16      // nodes per wave in k_mm
#define NPN       4       // nodes per wave in pull kernels (R13 NPN=8 was neutral-worse)

typedef _Float16 half4 __attribute__((ext_vector_type(4)));
typedef _Float16 half8 __attribute__((ext_vector_type(8)));
typedef __fp16   hf2   __attribute__((ext_vector_type(2)));   // builtin-compatible
typedef __fp16   hf8   __attribute__((ext_vector_type(8)));

#if defined(__has_builtin)
#if __has_builtin(__builtin_amdgcn_fdot2)
#define USE_DOT2 1
#endif
#endif

// ---- fused setup: block 0 -> prep W2, block 1 -> prep W3, rest -> zeroing ----
__device__ __forceinline__ void prepW_dev(const float* __restrict__ W,
                                          _Float16* __restrict__ out, int t) {
#pragma unroll
    for (int it = 0; it < 2; ++it) {
        int idx = t + it * 256;        // 512 (m, c) chunks
        int m = idx >> 3, c = idx & 7;
        half8 hv;
#pragma unroll
        for (int tt = 0; tt < 8; ++tt)
            hv[tt] = (_Float16)W[(8 * c + tt) * 64 + m];
        *(half8*)&out[m * 64 + ((c ^ (m & 7)) * 8)] = hv;
    }
}

__global__ void k_setup(const float* __restrict__ W2, const float* __restrict__ W3,
                        _Float16* __restrict__ WhA, _Float16* __restrict__ WhB,
                        int* __restrict__ gcur, float* __restrict__ poolz) {
    int blk = blockIdx.x;
    int t = threadIdx.x;
    if (blk == 0) { prepW_dev(W2, WhA, t); return; }
    if (blk == 1) { prepW_dev(W3, WhB, t); return; }
    int i = (blk - 2) * 256 + t;
    if (i < NBUCK) gcur[i] = 0;
    if (i < N_GRAPHS * D + N_GRAPHS) poolz[i] = 0.0f;
}

// ---- pass A: bucket edges by dst>>8 into fixed-capacity slabs.
// 1024-thread blocks (98 total): per-gcur-word atomic chain 391 -> 98 deep.
// staged entry packed to u32: (dst&255)<<17 | src  (src < 2^17; bucket from slab).
__global__ void __launch_bounds__(1024)
k_binA(const int* __restrict__ src, const int* __restrict__ dst,
       int* __restrict__ gcur, unsigned int* __restrict__ staged) {
    __shared__ int hist[NBUCK];
    __shared__ int boff[NBUCK];
    int tid = threadIdx.x;
    for (int i = tid; i < NBUCK; i += 1024) hist[i] = 0;
    __syncthreads();

    int e0 = blockIdx.x * EPB;
    int s_[16], d_[16], r_[16];
#pragma unroll
    for (int k = 0; k < 16; ++k) {
        int e = e0 + k * 1024 + tid;
        if (e < N_EDGES) {
            s_[k] = src[e];
            d_[k] = dst[e];
            r_[k] = atomicAdd(&hist[d_[k] >> 8], 1);
        } else {
            d_[k] = -1;
        }
    }
    __syncthreads();
    for (int b = tid; b < NBUCK; b += 1024) {
        int h = hist[b];
        boff[b] = (h > 0) ? atomicAdd(&gcur[b], h) : 0;
    }
    __syncthreads();
#pragma unroll
    for (int k = 0; k < 16; ++k) {
        if (d_[k] >= 0) {
            int b = d_[k] >> 8;
            staged[(size_t)b * BCAP + boff[b] + r_[k]] =
                ((unsigned)(d_[k] & 255) << 17) | (unsigned)s_[k];
        }
    }
}

// ---- scan bucket totals -> bucket edge-space starts ----
__global__ void k_scanB(const int* __restrict__ gcur, int* __restrict__ bstart) {
    __shared__ int s[512];
    int t = threadIdx.x;
    int v = (t < NBUCK) ? gcur[t] : 0;
    s[t] = v;
    __syncthreads();
    for (int off = 1; off < 512; off <<= 1) {
        int x = (t >= off) ? s[t - off] : 0;
        __syncthreads();
        s[t] += x;
        __syncthreads();
    }
    if (t < NBUCK) bstart[t] = s[t] - v;
    if (t == 0) bstart[NBUCK] = N_EDGES;
}

// ---- pass B: one block per bucket; LDS degree count + scan + place ----
__global__ void __launch_bounds__(256)
k_binB(const unsigned int* __restrict__ staged, const int* __restrict__ gcur,
       const int* __restrict__ bstart, int* __restrict__ esrc,
       int* __restrict__ base, float* __restrict__ dinv) {
    __shared__ int s[256];
    __shared__ int lbase[256];
    __shared__ int cur[256];
    int b = blockIdx.x;
    int t = threadIdx.x;
    int n0 = b << 8;
    int Eb = gcur[b];
    int Sb = bstart[b];
    const unsigned int* sl = staged + (size_t)b * BCAP;

    cur[t] = 0;
    __syncthreads();
    for (int k = t; k < Eb; k += 256) {
        int dl = (int)(sl[k] >> 17) & 255;
        atomicAdd(&cur[dl], 1);
    }
    __syncthreads();
    int v = cur[t];
    s[t] = v;
    __syncthreads();
    for (int off = 1; off < 256; off <<= 1) {
        int x = (t >= off) ? s[t - off] : 0;
        __syncthreads();
        s[t] += x;
        __syncthreads();
    }
    lbase[t] = s[t] - v;
    int gi = n0 + t;
    if (gi < N_NODES) {
        base[gi] = Sb + (s[t] - v);
        dinv[gi] = rsqrtf((float)v + 1.0f);   // +1 self-loop
    }
    if (b == 0 && t == 0) base[N_NODES] = N_EDGES;
    cur[t] = 0;
    __syncthreads();
    for (int k = t; k < Eb; k += 256) {
        unsigned int pd = sl[k];
        int dl = (int)(pd >> 17) & 255;
        int pos = Sb + lbase[dl] + atomicAdd(&cur[dl], 1);
        esrc[pos] = (int)(pd & 0x1FFFFu);
    }
}

// ------ matmul (layer 1): per-lane-feature, W1 column in registers ----------
__global__ void __launch_bounds__(256)
k_mm(const float* __restrict__ X, const float* __restrict__ W,
     const float* __restrict__ dinv, _Float16* __restrict__ Y16) {
    __shared__ float W1L[D * D];   // 16 KB raw [k][m]
    __shared__ float aSh[4][D];    // per-wave X row
    int tid = threadIdx.x;
#pragma unroll
    for (int it = 0; it < 4; ++it) {
        int idx = (tid + it * 256) * 4;
        *(float4*)&W1L[idx] = *(const float4*)(W + idx);
    }
    __syncthreads();

    int wv = tid >> 6, lane = tid & 63;
    float wreg[D];   // W1[k][lane] for all k
#pragma unroll
    for (int k = 0; k < D; ++k)
        wreg[k] = W1L[k * D + lane];

    int i0 = (blockIdx.x * 4 + wv) * MM_NPW;
    if (i0 >= N_NODES) return;
    int iEnd = i0 + MM_NPW; if (iEnd > N_NODES) iEnd = N_NODES;

    float xv = X[(size_t)i0 * D + lane];
    for (int i = i0; i < iEnd; ++i) {
        int inext = (i + 1 < N_NODES) ? (i + 1) : i;
        float xnext = X[(size_t)inext * D + lane];

        aSh[wv][lane] = xv;
        asm volatile("s_waitcnt lgkmcnt(0)" ::: "memory");

        float ac0 = 0.f, ac1 = 0.f, ac2 = 0.f, ac3 = 0.f;
#pragma unroll
        for (int c = 0; c < 16; ++c) {
            float4 a4 = *(const float4*)&aSh[wv][c * 4];
            ac0 = fmaf(a4.x, wreg[4 * c + 0], ac0);
            ac1 = fmaf(a4.y, wreg[4 * c + 1], ac1);
            ac2 = fmaf(a4.z, wreg[4 * c + 2], ac2);
            ac3 = fmaf(a4.w, wreg[4 * c + 3], ac3);
        }
        float acc = (ac0 + ac1) + (ac2 + ac3);
        Y16[(size_t)i * D + lane] = (_Float16)(acc * dinv[i]);
        xv = xnext;
    }
}

// ---- fused pull + matmul: R12 structure (NPN=4, no setup-prefetch) ----
__global__ void __launch_bounds__(256)
k_pullmm(const _Float16* __restrict__ H, const int* __restrict__ esrc,
         const int* __restrict__ base, const float* __restrict__ dinv,
         const float* __restrict__ b_in, const _Float16* __restrict__ Whg,
         _Float16* __restrict__ Hout) {
    __shared__ _Float16 WhL[D * D];        // 8KB swizzled Wt
    __shared__ float    red[4][8][D + 4];  // 8.5KB transpose-reduce tile
    __shared__ _Float16 aSh[4][D];         // 512B activation rows
    {
#pragma unroll
        for (int it = 0; it < 2; ++it) {
            int t = threadIdx.x + it * 256;
            *(half8*)&WhL[t * 8] = *(const half8*)&Whg[t * 8];
        }
    }
    __syncthreads();

    int wv   = threadIdx.x >> 6;
    int lane = threadIdx.x & 63;
    int g = lane >> 3, l = lane & 7;
    float bias = b_in[lane];
    int i0 = (blockIdx.x * 4 + wv) * NPN;

    for (int n = 0; n < NPN; ++n) {
        int i = i0 + n;
        int s0 = base[i], s1 = base[i + 1];

        float acc[8] = {0.f, 0.f, 0.f, 0.f, 0.f, 0.f, 0.f, 0.f};
        if (g == 0) {       // self contribution (group 0 only)
            half8 sv = *(const half8*)(H + (size_t)i * D + l * 8);
#pragma unroll
            for (int q = 0; q < 8; ++q) acc[q] = (float)sv[q];
        }

        int p = s0;
        while (p < s1) {
            int cnt = s1 - p;
            if (cnt > 64) cnt = 64;
            int ed = (lane < cnt) ? esrc[p + lane] : 0;
            int j = 0;
            for (; j + 32 <= cnt; j += 32) {
                int e0 = __shfl(ed, j + g, 64);
                int e1 = __shfl(ed, j + 8 + g, 64);
                int e2 = __shfl(ed, j + 16 + g, 64);
                int e3 = __shfl(ed, j + 24 + g, 64);
                half8 v0 = *(const half8*)(H + (size_t)(unsigned)e0 * D + l * 8);
                half8 v1 = *(const half8*)(H + (size_t)(unsigned)e1 * D + l * 8);
                half8 v2 = *(const half8*)(H + (size_t)(unsigned)e2 * D + l * 8);
                half8 v3 = *(const half8*)(H + (size_t)(unsigned)e3 * D + l * 8);
                half8 s01 = v0 + v1;
                half8 s23 = v2 + v3;
#pragma unroll
                for (int q = 0; q < 8; ++q)
                    acc[q] += (float)s01[q] + (float)s23[q];
            }
            for (; j + 16 <= cnt; j += 16) {
                int e0 = __shfl(ed, j + g, 64);
                int e1 = __shfl(ed, j + 8 + g, 64);
                half8 v0 = *(const half8*)(H + (size_t)(unsigned)e0 * D + l * 8);
                half8 v1 = *(const half8*)(H + (size_t)(unsigned)e1 * D + l * 8);
                half8 s01 = v0 + v1;
#pragma unroll
                for (int q = 0; q < 8; ++q) acc[q] += (float)s01[q];
            }
            for (; j + 8 <= cnt; j += 8) {
                int e0 = __shfl(ed, j + g, 64);
                half8 v0 = *(const half8*)(H + (size_t)(unsigned)e0 * D + l * 8);
#pragma unroll
                for (int q = 0; q < 8; ++q) acc[q] += (float)v0[q];
            }
            if (j < cnt) {
                int idx = j + g;
                int e0 = __shfl(ed, idx & 63, 64);
                if (idx < cnt) {
                    half8 v0 = *(const half8*)(H + (size_t)(unsigned)e0 * D + l * 8);
#pragma unroll
                    for (int q = 0; q < 8; ++q) acc[q] += (float)v0[q];
                }
            }
            p += cnt;
        }

        // ---- LDS transpose-reduce (2 independent add chains) ----
        *(float4*)&red[wv][g][l * 8]     = make_float4(acc[0], acc[1], acc[2], acc[3]);
        *(float4*)&red[wv][g][l * 8 + 4] = make_float4(acc[4], acc[5], acc[6], acc[7]);
        asm volatile("s_waitcnt lgkmcnt(0)" ::: "memory");
        float ag0 = 0.f, ag1 = 0.f;
#pragma unroll
        for (int gg = 0; gg < 8; gg += 2) {
            ag0 += red[wv][gg][lane];
            ag1 += red[wv][gg + 1][lane];
        }
        float agg = ag0 + ag1;

        float di = dinv[i];
        float av = fmaxf(fmaf(agg, di, bias), 0.f);
        aSh[wv][lane] = (_Float16)av;
        asm volatile("s_waitcnt lgkmcnt(0)" ::: "memory");

        // ---- dot2 epilogue: 4 independent accumulators ----
        float p0 = 0.f, p1 = 0.f, p2 = 0.f, p3 = 0.f;
#pragma unroll
        for (int c = 0; c < 8; ++c) {
            hf8 a8 = *(const hf8*)&aSh[wv][c * 8];                           // broadcast
            hf8 w8 = *(const hf8*)&WhL[lane * 64 + ((c ^ (lane & 7)) * 8)];  // swizzled
#ifdef USE_DOT2
            hf2 a0; a0.x = a8[0]; a0.y = a8[1];
            hf2 a1; a1.x = a8[2]; a1.y = a8[3];
            hf2 a2; a2.x = a8[4]; a2.y = a8[5];
            hf2 a3; a3.x = a8[6]; a3.y = a8[7];
            hf2 w0; w0.x = w8[0]; w0.y = w8[1];
            hf2 w1; w1.x = w8[2]; w1.y = w8[3];
            hf2 w2; w2.x = w8[4]; w2.y = w8[5];
            hf2 w3; w3.x = w8[6]; w3.y = w8[7];
            p0 = __builtin_amdgcn_fdot2(a0, w0, p0, false);
            p1 = __builtin_amdgcn_fdot2(a1, w1, p1, false);
            p2 = __builtin_amdgcn_fdot2(a2, w2, p2, false);
            p3 = __builtin_amdgcn_fdot2(a3, w3, p3, false);
#else
#pragma unroll
            for (int t = 0; t < 8; t += 4) {
                p0 = fmaf((float)a8[t],     (float)w8[t],     p0);
                p1 = fmaf((float)a8[t + 1], (float)w8[t + 1], p1);
                p2 = fmaf((float)a8[t + 2], (float)w8[t + 2], p2);
                p3 = fmaf((float)a8[t + 3], (float)w8[t + 3], p3);
            }
#endif
        }
        float part = (p0 + p1) + (p2 + p3);
        Hout[(size_t)i * D + lane] = (_Float16)(part * di);
    }
}

// ---- final pull (layer 3): R12 structure, AGG16 out (separate pooling) ----
__global__ void __launch_bounds__(256)
k_pull(const _Float16* __restrict__ H, const int* __restrict__ esrc,
       const int* __restrict__ base, const float* __restrict__ dinv,
       const float* __restrict__ b, _Float16* __restrict__ AGG16) {
    __shared__ float red[4][8][D + 4];
    int wv   = threadIdx.x >> 6;
    int lane = threadIdx.x & 63;
    int g = lane >> 3, l = lane & 7;
    float bias = b[lane];
    int i0 = (blockIdx.x * 4 + wv) * NPN;

    for (int n = 0; n < NPN; ++n) {
        int i = i0 + n;
        int s0 = base[i], s1 = base[i + 1];

        float acc[8] = {0.f, 0.f, 0.f, 0.f, 0.f, 0.f, 0.f, 0.f};
        if (g == 0) {
            half8 sv = *(const half8*)(H + (size_t)i * D + l * 8);
#pragma unroll
            for (int q = 0; q < 8; ++q) acc[q] = (float)sv[q];
        }

        int p = s0;
        while (p < s1) {
            int cnt = s1 - p;
            if (cnt > 64) cnt = 64;
            int ed = (lane < cnt) ? esrc[p + lane] : 0;
            int j = 0;
            for (; j + 32 <= cnt; j += 32) {
                int e0 = __shfl(ed, j + g, 64);
                int e1 = __shfl(ed, j + 8 + g, 64);
                int e2 = __shfl(ed, j + 16 + g, 64);
                int e3 = __shfl(ed, j + 24 + g, 64);
                half8 v0 = *(const half8*)(H + (size_t)(unsigned)e0 * D + l * 8);
                half8 v1 = *(const half8*)(H + (size_t)(unsigned)e1 * D + l * 8);
                half8 v2 = *(const half8*)(H + (size_t)(unsigned)e2 * D + l * 8);
                half8 v3 = *(const half8*)(H + (size_t)(unsigned)e3 * D + l * 8);
                half8 s01 = v0 + v1;
                half8 s23 = v2 + v3;
#pragma unroll
                for (int q = 0; q < 8; ++q)
                    acc[q] += (float)s01[q] + (float)s23[q];
            }
            for (; j + 16 <= cnt; j += 16) {
                int e0 = __shfl(ed, j + g, 64);
                int e1 = __shfl(ed, j + 8 + g, 64);
                half8 v0 = *(const half8*)(H + (size_t)(unsigned)e0 * D + l * 8);
                half8 v1 = *(const half8*)(H + (size_t)(unsigned)e1 * D + l * 8);
                half8 s01 = v0 + v1;
#pragma unroll
                for (int q = 0; q < 8; ++q) acc[q] += (float)s01[q];
            }
            for (; j + 8 <= cnt; j += 8) {
                int e0 = __shfl(ed, j + g, 64);
                half8 v0 = *(const half8*)(H + (size_t)(unsigned)e0 * D + l * 8);
#pragma unroll
                for (int q = 0; q < 8; ++q) acc[q] += (float)v0[q];
            }
            if (j < cnt) {
                int idx = j + g;
                int e0 = __shfl(ed, idx & 63, 64);
                if (idx < cnt) {
                    half8 v0 = *(const half8*)(H + (size_t)(unsigned)e0 * D + l * 8);
#pragma unroll
                    for (int q = 0; q < 8; ++q) acc[q] += (float)v0[q];
                }
            }
            p += cnt;
        }

        *(float4*)&red[wv][g][l * 8]     = make_float4(acc[0], acc[1], acc[2], acc[3]);
        *(float4*)&red[wv][g][l * 8 + 4] = make_float4(acc[4], acc[5], acc[6], acc[7]);
        asm volatile("s_waitcnt lgkmcnt(0)" ::: "memory");
        float ag0 = 0.f, ag1 = 0.f;
#pragma unroll
        for (int gg = 0; gg < 8; gg += 2) {
            ag0 += red[wv][gg][lane];
            ag1 += red[wv][gg + 1][lane];
        }
        float agg = ag0 + ag1;
        asm volatile("s_waitcnt lgkmcnt(0)" ::: "memory");

        AGG16[(size_t)i * D + lane] = (_Float16)fmaf(agg, dinv[i], bias);
    }
}

// ---- segment-sorted pooling (fp16 in, fp32 accumulate, fused counts) ----
__global__ void __launch_bounds__(256)
k_pool_seg(const _Float16* __restrict__ H16, const int* __restrict__ seg,
           float* __restrict__ pooled, float* __restrict__ counts) {
    int wave = threadIdx.x >> 6;
    int lane = threadIdx.x & 63;
    int n0 = (blockIdx.x * 4 + wave) * 64;
    if (n0 >= N_NODES) return;
    int nEnd = n0 + 64;
    if (nEnd > N_NODES) nEnd = N_NODES;
    int cur = seg[n0];
    float acc = 0.0f;
    int run = 0;
    for (int n = n0; n < nEnd; ++n) {
        int gsg = seg[n];  // wave-uniform
        if (gsg != cur) {
            atomicAdd(&pooled[(size_t)cur * D + lane], acc);
            if (lane == 0) atomicAdd(&counts[cur], (float)run);
            acc = 0.0f; run = 0;
            cur = gsg;
        }
        acc += (float)H16[(size_t)n * D + lane];
        run += 1;
    }
    atomicAdd(&pooled[(size_t)cur * D + lane], acc);
    if (lane == 0) atomicAdd(&counts[cur], (float)run);
}

// ---------------- head ----------------
__global__ void k_out(const float* __restrict__ pooled, const float* __restrict__ counts,
                      const float* __restrict__ Wout, const float* __restrict__ bout,
                      float* __restrict__ out) {
    __shared__ float prow[D];
    int g = blockIdx.x;
    int t = threadIdx.x;
    if (t < D) prow[t] = pooled[(size_t)g * D + t] / fmaxf(counts[g], 1.0f);
    __syncthreads();
    if (t < N_TARGETS) {
        float acc = bout[t];
#pragma unroll
        for (int k = 0; k < D; ++k)
            acc = fmaf(prow[k], Wout[k * N_TARGETS + t], acc);
        out[g * N_TARGETS + t] = acc;
    }
}

// ---------------- driver ----------------

extern "C" void kernel_launch(void* const* d_in, const int* in_sizes, int n_in,
                              void* d_out, int out_size, void* d_ws, size_t ws_size,
                              hipStream_t stream) {
    const float* x    = (const float*)d_in[0];
    const float* W1   = (const float*)d_in[1];
    const float* b1   = (const float*)d_in[2];
    const float* W2   = (const float*)d_in[3];
    const float* b2   = (const float*)d_in[4];
    const float* W3   = (const float*)d_in[5];
    const float* b3   = (const float*)d_in[6];
    const float* Wout = (const float*)d_in[7];
    const float* bout = (const float*)d_in[8];
    const int*   eidx = (const int*)d_in[9];
    const int*   seg  = (const int*)d_in[10];
    const int* src = eidx;
    const int* dst = eidx + N_EDGES;
    float* out = (float*)d_out;

    // workspace layout (~33 MB). staged (9.6 MB u32) aliases H16A (dead
    // during CSR build); AGG16 aliases H16B (dead after pullmm#2).
    _Float16* H16A   = (_Float16*)d_ws;                       // 6.4M halfs (12.8MB)
    _Float16* H16B   = H16A + (size_t)N_NODES * D;            // 6.4M halfs
    _Float16* AGG16  = H16B;                                  // alias
    unsigned int* staged = (unsigned int*)d_ws;               // alias: 391*6144 u32
    int*      esrc   = (int*)(H16B + (size_t)N_NODES * D);    // 1.6M
    float*    dinv   = (float*)(esrc + N_EDGES);              // 100k
    int*      base   = (int*)(dinv + N_NODES);                // 100k+1 (+pad)
    float*    pooled = (float*)(base + N_NODES + 4);          // 32768
    float*    counts = pooled + N_GRAPHS * D;                 // 512
    int*      gcur   = (int*)(counts + N_GRAPHS);             // 391 (+pad to 512)
    int*      bstart = gcur + 512;                            // 392 (+pad to 512)
    _Float16* WhA    = (_Float16*)(bstart + 512);             // 4096 halfs (8KB)
    _Float16* WhB    = WhA + 4096;                            // 4096 halfs (8KB)

    const int NB = (N_NODES + 255) / 256;  // 391

    // ---- fused setup: W2/W3 fp16 prep + cursor/pool zeroing (one launch) ----
    k_setup<<<132, 256, 0, stream>>>(W2, W3, WhA, WhB, gcur, pooled);

    // ---- CSR build: slab-bucketed scatter with in-bucket degree counting ----
    k_binA<<<(N_EDGES + EPB - 1) / EPB, 1024, 0, stream>>>(src, dst, gcur, staged);
    k_scanB<<<1, 512, 0, stream>>>(gcur, bstart);
    k_binB<<<NBUCK, 256, 0, stream>>>(staged, gcur, bstart, esrc, base, dinv);

    // ---- 3 GCN layers (mm1 separate; mm2/mm3 fused into pulls) ----
    const int MMB = (N_NODES + 4 * MM_NPW - 1) / (4 * MM_NPW);  // 1563
    const int PB  = N_NODES / (4 * NPN);                        // 6250
    k_mm<<<MMB, 256, 0, stream>>>(x, W1, dinv, H16A);
    k_pullmm<<<PB, 256, 0, stream>>>(H16A, esrc, base, dinv, b1, WhA, H16B);
    k_pullmm<<<PB, 256, 0, stream>>>(H16B, esrc, base, dinv, b2, WhB, H16A);
    k_pull<<<PB, 256, 0, stream>>>(H16A, esrc, base, dinv, b3, AGG16);

    // ---- mean pool (sorted-segment, fused counts) + head ----
    k_pool_seg<<<NB, 256, 0, stream>>>(AGG16, seg, pooled, counts);
    k_out<<<N_GRAPHS, 128, 0, stream>>>(pooled, counts, Wout, bout, out);
}

// Round 16
// 304.722 us; speedup vs baseline: 1.0444x; 1.0170x over previous
//
#include <hip/hip_runtime.h>

#define N_NODES   100000
#define N_EDGES   1600000
#define D         64
#define N_TARGETS 100
#define N_GRAPHS  512
#define NBUCK     391     // ceil(N_NODES / 256): bucket b = dst >> 8
#define EPB       16384   // edges per block in pass A (1024 thr x 16)
#define BCAP      6144    // bucket slab capacity (Poisson(4096) + 32 sigma)
#define MM_NPW    16      // nodes per wave in k_mm
#define NPN       4       // nodes per wave in pull kernels

typedef _Float16 half4 __attribute__((ext_vector_type(4)));
typedef _Float16 half8 __attribute__((ext_vector_type(8)));
typedef __fp16   hf2   __attribute__((ext_vector_type(2)));   // builtin-compatible
typedef __fp16   hf8   __attribute__((ext_vector_type(8)));

#if defined(__has_builtin)
#if __has_builtin(__builtin_amdgcn_fdot2)
#define USE_DOT2 1
#endif
#endif

// ---- fused setup: block 0 -> prep W2, block 1 -> prep W3, rest -> zeroing ----
__device__ __forceinline__ void prepW_dev(const float* __restrict__ W,
                                          _Float16* __restrict__ out, int t) {
#pragma unroll
    for (int it = 0; it < 2; ++it) {
        int idx = t + it * 256;        // 512 (m, c) chunks
        int m = idx >> 3, c = idx & 7;
        half8 hv;
#pragma unroll
        for (int tt = 0; tt < 8; ++tt)
            hv[tt] = (_Float16)W[(8 * c + tt) * 64 + m];
        *(half8*)&out[m * 64 + ((c ^ (m & 7)) * 8)] = hv;
    }
}

__global__ void k_setup(const float* __restrict__ W2, const float* __restrict__ W3,
                        _Float16* __restrict__ WhA, _Float16* __restrict__ WhB,
                        int* __restrict__ gcur, float* __restrict__ poolz) {
    int blk = blockIdx.x;
    int t = threadIdx.x;
    if (blk == 0) { prepW_dev(W2, WhA, t); return; }
    if (blk == 1) { prepW_dev(W3, WhB, t); return; }
    int i = (blk - 2) * 256 + t;
    if (i < NBUCK) gcur[i] = 0;
    if (i < N_GRAPHS * D + N_GRAPHS) poolz[i] = 0.0f;
}

// ---- pass A: bucket edges by dst>>8 into fixed-capacity slabs (u32-packed) ----
__global__ void __launch_bounds__(1024)
k_binA(const int* __restrict__ src, const int* __restrict__ dst,
       int* __restrict__ gcur, unsigned int* __restrict__ staged) {
    __shared__ int hist[NBUCK];
    __shared__ int boff[NBUCK];
    int tid = threadIdx.x;
    for (int i = tid; i < NBUCK; i += 1024) hist[i] = 0;
    __syncthreads();

    int e0 = blockIdx.x * EPB;
    int s_[16], d_[16], r_[16];
#pragma unroll
    for (int k = 0; k < 16; ++k) {
        int e = e0 + k * 1024 + tid;
        if (e < N_EDGES) {
            s_[k] = src[e];
            d_[k] = dst[e];
            r_[k] = atomicAdd(&hist[d_[k] >> 8], 1);
        } else {
            d_[k] = -1;
        }
    }
    __syncthreads();
    for (int b = tid; b < NBUCK; b += 1024) {
        int h = hist[b];
        boff[b] = (h > 0) ? atomicAdd(&gcur[b], h) : 0;
    }
    __syncthreads();
#pragma unroll
    for (int k = 0; k < 16; ++k) {
        if (d_[k] >= 0) {
            int b = d_[k] >> 8;
            staged[(size_t)b * BCAP + boff[b] + r_[k]] =
                ((unsigned)(d_[k] & 255) << 17) | (unsigned)s_[k];
        }
    }
}

// ---- scan bucket totals -> bucket edge-space starts ----
__global__ void k_scanB(const int* __restrict__ gcur, int* __restrict__ bstart) {
    __shared__ int s[512];
    int t = threadIdx.x;
    int v = (t < NBUCK) ? gcur[t] : 0;
    s[t] = v;
    __syncthreads();
    for (int off = 1; off < 512; off <<= 1) {
        int x = (t >= off) ? s[t - off] : 0;
        __syncthreads();
        s[t] += x;
        __syncthreads();
    }
    if (t < NBUCK) bstart[t] = s[t] - v;
    if (t == 0) bstart[NBUCK] = N_EDGES;
}

// ---- pass B: one block per bucket; LDS degree count + scan + place ----
__global__ void __launch_bounds__(256)
k_binB(const unsigned int* __restrict__ staged, const int* __restrict__ gcur,
       const int* __restrict__ bstart, int* __restrict__ esrc,
       int* __restrict__ base, float* __restrict__ dinv) {
    __shared__ int s[256];
    __shared__ int lbase[256];
    __shared__ int cur[256];
    int b = blockIdx.x;
    int t = threadIdx.x;
    int n0 = b << 8;
    int Eb = gcur[b];
    int Sb = bstart[b];
    const unsigned int* sl = staged + (size_t)b * BCAP;

    cur[t] = 0;
    __syncthreads();
    for (int k = t; k < Eb; k += 256) {
        int dl = (int)(sl[k] >> 17) & 255;
        atomicAdd(&cur[dl], 1);
    }
    __syncthreads();
    int v = cur[t];
    s[t] = v;
    __syncthreads();
    for (int off = 1; off < 256; off <<= 1) {
        int x = (t >= off) ? s[t - off] : 0;
        __syncthreads();
        s[t] += x;
        __syncthreads();
    }
    lbase[t] = s[t] - v;
    int gi = n0 + t;
    if (gi < N_NODES) {
        base[gi] = Sb + (s[t] - v);
        dinv[gi] = rsqrtf((float)v + 1.0f);   // +1 self-loop
    }
    if (b == 0 && t == 0) base[N_NODES] = N_EDGES;
    cur[t] = 0;
    __syncthreads();
    for (int k = t; k < Eb; k += 256) {
        unsigned int pd = sl[k];
        int dl = (int)(pd >> 17) & 255;
        int pos = Sb + lbase[dl] + atomicAdd(&cur[dl], 1);
        esrc[pos] = (int)(pd & 0x1FFFFu);
    }
}

// ------ matmul (layer 1): per-lane-feature, W1 column in registers ----------
__global__ void __launch_bounds__(256)
k_mm(const float* __restrict__ X, const float* __restrict__ W,
     const float* __restrict__ dinv, _Float16* __restrict__ Y16) {
    __shared__ float W1L[D * D];   // 16 KB raw [k][m]
    __shared__ float aSh[4][D];    // per-wave X row
    int tid = threadIdx.x;
#pragma unroll
    for (int it = 0; it < 4; ++it) {
        int idx = (tid + it * 256) * 4;
        *(float4*)&W1L[idx] = *(const float4*)(W + idx);
    }
    __syncthreads();

    int wv = tid >> 6, lane = tid & 63;
    float wreg[D];   // W1[k][lane] for all k
#pragma unroll
    for (int k = 0; k < D; ++k)
        wreg[k] = W1L[k * D + lane];

    int i0 = (blockIdx.x * 4 + wv) * MM_NPW;
    if (i0 >= N_NODES) return;
    int iEnd = i0 + MM_NPW; if (iEnd > N_NODES) iEnd = N_NODES;

    float xv = X[(size_t)i0 * D + lane];
    for (int i = i0; i < iEnd; ++i) {
        int inext = (i + 1 < N_NODES) ? (i + 1) : i;
        float xnext = X[(size_t)inext * D + lane];

        aSh[wv][lane] = xv;
        asm volatile("s_waitcnt lgkmcnt(0)" ::: "memory");

        float ac0 = 0.f, ac1 = 0.f, ac2 = 0.f, ac3 = 0.f;
#pragma unroll
        for (int c = 0; c < 16; ++c) {
            float4 a4 = *(const float4*)&aSh[wv][c * 4];
            ac0 = fmaf(a4.x, wreg[4 * c + 0], ac0);
            ac1 = fmaf(a4.y, wreg[4 * c + 1], ac1);
            ac2 = fmaf(a4.z, wreg[4 * c + 2], ac2);
            ac3 = fmaf(a4.w, wreg[4 * c + 3], ac3);
        }
        float acc = (ac0 + ac1) + (ac2 + ac3);
        Y16[(size_t)i * D + lane] = (_Float16)(acc * dinv[i]);
        xv = xnext;
    }
}

// ---- fused pull + matmul: R12 structure (NPN=4, no setup-prefetch) ----
__global__ void __launch_bounds__(256)
k_pullmm(const _Float16* __restrict__ H, const int* __restrict__ esrc,
         const int* __restrict__ base, const float* __restrict__ dinv,
         const float* __restrict__ b_in, const _Float16* __restrict__ Whg,
         _Float16* __restrict__ Hout) {
    __shared__ _Float16 WhL[D * D];        // 8KB swizzled Wt
    __shared__ float    red[4][8][D + 4];  // 8.5KB transpose-reduce tile
    __shared__ _Float16 aSh[4][D];         // 512B activation rows
    {
#pragma unroll
        for (int it = 0; it < 2; ++it) {
            int t = threadIdx.x + it * 256;
            *(half8*)&WhL[t * 8] = *(const half8*)&Whg[t * 8];
        }
    }
    __syncthreads();

    int wv   = threadIdx.x >> 6;
    int lane = threadIdx.x & 63;
    int g = lane >> 3, l = lane & 7;
    float bias = b_in[lane];
    int i0 = (blockIdx.x * 4 + wv) * NPN;

    for (int n = 0; n < NPN; ++n) {
        int i = i0 + n;
        int s0 = base[i], s1 = base[i + 1];

        float acc[8] = {0.f, 0.f, 0.f, 0.f, 0.f, 0.f, 0.f, 0.f};
        if (g == 0) {       // self contribution (group 0 only)
            half8 sv = *(const half8*)(H + (size_t)i * D + l * 8);
#pragma unroll
            for (int q = 0; q < 8; ++q) acc[q] = (float)sv[q];
        }

        int p = s0;
        while (p < s1) {
            int cnt = s1 - p;
            if (cnt > 64) cnt = 64;
            int ed = (lane < cnt) ? esrc[p + lane] : 0;
            int j = 0;
            for (; j + 32 <= cnt; j += 32) {
                int e0 = __shfl(ed, j + g, 64);
                int e1 = __shfl(ed, j + 8 + g, 64);
                int e2 = __shfl(ed, j + 16 + g, 64);
                int e3 = __shfl(ed, j + 24 + g, 64);
                half8 v0 = *(const half8*)(H + (size_t)(unsigned)e0 * D + l * 8);
                half8 v1 = *(const half8*)(H + (size_t)(unsigned)e1 * D + l * 8);
                half8 v2 = *(const half8*)(H + (size_t)(unsigned)e2 * D + l * 8);
                half8 v3 = *(const half8*)(H + (size_t)(unsigned)e3 * D + l * 8);
                half8 s01 = v0 + v1;
                half8 s23 = v2 + v3;
#pragma unroll
                for (int q = 0; q < 8; ++q)
                    acc[q] += (float)s01[q] + (float)s23[q];
            }
            for (; j + 16 <= cnt; j += 16) {
                int e0 = __shfl(ed, j + g, 64);
                int e1 = __shfl(ed, j + 8 + g, 64);
                half8 v0 = *(const half8*)(H + (size_t)(unsigned)e0 * D + l * 8);
                half8 v1 = *(const half8*)(H + (size_t)(unsigned)e1 * D + l * 8);
                half8 s01 = v0 + v1;
#pragma unroll
                for (int q = 0; q < 8; ++q) acc[q] += (float)s01[q];
            }
            for (; j + 8 <= cnt; j += 8) {
                int e0 = __shfl(ed, j + g, 64);
                half8 v0 = *(const half8*)(H + (size_t)(unsigned)e0 * D + l * 8);
#pragma unroll
                for (int q = 0; q < 8; ++q) acc[q] += (float)v0[q];
            }
            if (j < cnt) {
                int idx = j + g;
                int e0 = __shfl(ed, idx & 63, 64);
                if (idx < cnt) {
                    half8 v0 = *(const half8*)(H + (size_t)(unsigned)e0 * D + l * 8);
#pragma unroll
                    for (int q = 0; q < 8; ++q) acc[q] += (float)v0[q];
                }
            }
            p += cnt;
        }

        // ---- LDS transpose-reduce (2 independent add chains) ----
        *(float4*)&red[wv][g][l * 8]     = make_float4(acc[0], acc[1], acc[2], acc[3]);
        *(float4*)&red[wv][g][l * 8 + 4] = make_float4(acc[4], acc[5], acc[6], acc[7]);
        asm volatile("s_waitcnt lgkmcnt(0)" ::: "memory");
        float ag0 = 0.f, ag1 = 0.f;
#pragma unroll
        for (int gg = 0; gg < 8; gg += 2) {
            ag0 += red[wv][gg][lane];
            ag1 += red[wv][gg + 1][lane];
        }
        float agg = ag0 + ag1;

        float di = dinv[i];
        float av = fmaxf(fmaf(agg, di, bias), 0.f);
        aSh[wv][lane] = (_Float16)av;
        asm volatile("s_waitcnt lgkmcnt(0)" ::: "memory");

        // ---- dot2 epilogue: 4 independent accumulators ----
        float p0 = 0.f, p1 = 0.f, p2 = 0.f, p3 = 0.f;
#pragma unroll
        for (int c = 0; c < 8; ++c) {
            hf8 a8 = *(const hf8*)&aSh[wv][c * 8];                           // broadcast
            hf8 w8 = *(const hf8*)&WhL[lane * 64 + ((c ^ (lane & 7)) * 8)];  // swizzled
#ifdef USE_DOT2
            hf2 a0; a0.x = a8[0]; a0.y = a8[1];
            hf2 a1; a1.x = a8[2]; a1.y = a8[3];
            hf2 a2; a2.x = a8[4]; a2.y = a8[5];
            hf2 a3; a3.x = a8[6]; a3.y = a8[7];
            hf2 w0; w0.x = w8[0]; w0.y = w8[1];
            hf2 w1; w1.x = w8[2]; w1.y = w8[3];
            hf2 w2; w2.x = w8[4]; w2.y = w8[5];
            hf2 w3; w3.x = w8[6]; w3.y = w8[7];
            p0 = __builtin_amdgcn_fdot2(a0, w0, p0, false);
            p1 = __builtin_amdgcn_fdot2(a1, w1, p1, false);
            p2 = __builtin_amdgcn_fdot2(a2, w2, p2, false);
            p3 = __builtin_amdgcn_fdot2(a3, w3, p3, false);
#else
#pragma unroll
            for (int t = 0; t < 8; t += 4) {
                p0 = fmaf((float)a8[t],     (float)w8[t],     p0);
                p1 = fmaf((float)a8[t + 1], (float)w8[t + 1], p1);
                p2 = fmaf((float)a8[t + 2], (float)w8[t + 2], p2);
                p3 = fmaf((float)a8[t + 3], (float)w8[t + 3], p3);
            }
#endif
        }
        float part = (p0 + p1) + (p2 + p3);
        Hout[(size_t)i * D + lane] = (_Float16)(part * di);
    }
}

// ---- final pull (layer 3) + two-level fused mean-pool:
// per-node fp32 val -> LDS pool slot (seg[i]-g0, <=16 slots/block) via LDS
// atomics -> ONE global atomic per non-empty slot per lane at block end
// (~440K atomics spread over the whole kernel vs R10's 3.2M in bursts).
// Kills AGG16 write+read (25.6 MB) and the k_pool_seg launch.
__global__ void __launch_bounds__(256)
k_pull(const _Float16* __restrict__ H, const int* __restrict__ esrc,
       const int* __restrict__ base, const float* __restrict__ dinv,
       const float* __restrict__ b, const int* __restrict__ seg,
       float* __restrict__ pooled, float* __restrict__ counts) {
    __shared__ float red[4][8][D + 4];
    __shared__ float poolL[16][D];   // 4KB block-local pool
    __shared__ float cntL[16];
    int wv   = threadIdx.x >> 6;
    int lane = threadIdx.x & 63;
    int g = lane >> 3, l = lane & 7;
    float bias = b[lane];
    int ib0 = blockIdx.x * 16;          // block's first node
    int g0  = seg[ib0];                 // block's first graph (seg sorted)
    int i0 = ib0 + wv * NPN;

    {   // zero the block pool
        int t = threadIdx.x;
#pragma unroll
        for (int z = 0; z < 4; ++z) poolL[(t * 4 + z) >> 6][(t * 4 + z) & 63] = 0.f;
        if (t < 16) cntL[t] = 0.f;
    }
    __syncthreads();

    for (int n = 0; n < NPN; ++n) {
        int i = i0 + n;
        int s0 = base[i], s1 = base[i + 1];

        float acc[8] = {0.f, 0.f, 0.f, 0.f, 0.f, 0.f, 0.f, 0.f};
        if (g == 0) {
            half8 sv = *(const half8*)(H + (size_t)i * D + l * 8);
#pragma unroll
            for (int q = 0; q < 8; ++q) acc[q] = (float)sv[q];
        }

        int p = s0;
        while (p < s1) {
            int cnt = s1 - p;
            if (cnt > 64) cnt = 64;
            int ed = (lane < cnt) ? esrc[p + lane] : 0;
            int j = 0;
            for (; j + 32 <= cnt; j += 32) {
                int e0 = __shfl(ed, j + g, 64);
                int e1 = __shfl(ed, j + 8 + g, 64);
                int e2 = __shfl(ed, j + 16 + g, 64);
                int e3 = __shfl(ed, j + 24 + g, 64);
                half8 v0 = *(const half8*)(H + (size_t)(unsigned)e0 * D + l * 8);
                half8 v1 = *(const half8*)(H + (size_t)(unsigned)e1 * D + l * 8);
                half8 v2 = *(const half8*)(H + (size_t)(unsigned)e2 * D + l * 8);
                half8 v3 = *(const half8*)(H + (size_t)(unsigned)e3 * D + l * 8);
                half8 s01 = v0 + v1;
                half8 s23 = v2 + v3;
#pragma unroll
                for (int q = 0; q < 8; ++q)
                    acc[q] += (float)s01[q] + (float)s23[q];
            }
            for (; j + 16 <= cnt; j += 16) {
                int e0 = __shfl(ed, j + g, 64);
                int e1 = __shfl(ed, j + 8 + g, 64);
                half8 v0 = *(const half8*)(H + (size_t)(unsigned)e0 * D + l * 8);
                half8 v1 = *(const half8*)(H + (size_t)(unsigned)e1 * D + l * 8);
                half8 s01 = v0 + v1;
#pragma unroll
                for (int q = 0; q < 8; ++q) acc[q] += (float)s01[q];
            }
            for (; j + 8 <= cnt; j += 8) {
                int e0 = __shfl(ed, j + g, 64);
                half8 v0 = *(const half8*)(H + (size_t)(unsigned)e0 * D + l * 8);
#pragma unroll
                for (int q = 0; q < 8; ++q) acc[q] += (float)v0[q];
            }
            if (j < cnt) {
                int idx = j + g;
                int e0 = __shfl(ed, idx & 63, 64);
                if (idx < cnt) {
                    half8 v0 = *(const half8*)(H + (size_t)(unsigned)e0 * D + l * 8);
#pragma unroll
                    for (int q = 0; q < 8; ++q) acc[q] += (float)v0[q];
                }
            }
            p += cnt;
        }

        *(float4*)&red[wv][g][l * 8]     = make_float4(acc[0], acc[1], acc[2], acc[3]);
        *(float4*)&red[wv][g][l * 8 + 4] = make_float4(acc[4], acc[5], acc[6], acc[7]);
        asm volatile("s_waitcnt lgkmcnt(0)" ::: "memory");
        float ag0 = 0.f, ag1 = 0.f;
#pragma unroll
        for (int gg = 0; gg < 8; gg += 2) {
            ag0 += red[wv][gg][lane];
            ag1 += red[wv][gg + 1][lane];
        }
        float agg = ag0 + ag1;
        asm volatile("s_waitcnt lgkmcnt(0)" ::: "memory");

        float val = fmaf(agg, dinv[i], bias);   // fp32, no fp16 rounding
        int slot = seg[i] - g0;                 // 0..15 (seg sorted, 16 nodes)
        atomicAdd(&poolL[slot][lane], val);     // LDS atomic (<=4-way)
        if (lane == 0) atomicAdd(&cntL[slot], 1.0f);
    }
    __syncthreads();

    // block flush: wave wv handles slots wv, wv+4, wv+8, wv+12
#pragma unroll
    for (int k = 0; k < 4; ++k) {
        int slot = wv + 4 * k;
        float c = cntL[slot];
        if (c > 0.f) {
            atomicAdd(&pooled[(size_t)(g0 + slot) * D + lane], poolL[slot][lane]);
            if (lane == 0) atomicAdd(&counts[g0 + slot], c);
        }
    }
}

// ---------------- head ----------------
__global__ void k_out(const float* __restrict__ pooled, const float* __restrict__ counts,
                      const float* __restrict__ Wout, const float* __restrict__ bout,
                      float* __restrict__ out) {
    __shared__ float prow[D];
    int g = blockIdx.x;
    int t = threadIdx.x;
    if (t < D) prow[t] = pooled[(size_t)g * D + t] / fmaxf(counts[g], 1.0f);
    __syncthreads();
    if (t < N_TARGETS) {
        float acc = bout[t];
#pragma unroll
        for (int k = 0; k < D; ++k)
            acc = fmaf(prow[k], Wout[k * N_TARGETS + t], acc);
        out[g * N_TARGETS + t] = acc;
    }
}

// ---------------- driver ----------------

extern "C" void kernel_launch(void* const* d_in, const int* in_sizes, int n_in,
                              void* d_out, int out_size, void* d_ws, size_t ws_size,
                              hipStream_t stream) {
    const float* x    = (const float*)d_in[0];
    const float* W1   = (const float*)d_in[1];
    const float* b1   = (const float*)d_in[2];
    const float* W2   = (const float*)d_in[3];
    const float* b2   = (const float*)d_in[4];
    const float* W3   = (const float*)d_in[5];
    const float* b3   = (const float*)d_in[6];
    const float* Wout = (const float*)d_in[7];
    const float* bout = (const float*)d_in[8];
    const int*   eidx = (const int*)d_in[9];
    const int*   seg  = (const int*)d_in[10];
    const int* src = eidx;
    const int* dst = eidx + N_EDGES;
    float* out = (float*)d_out;

    // workspace layout (~33 MB). staged (9.6 MB u32) aliases H16A (dead
    // during CSR build).
    _Float16* H16A   = (_Float16*)d_ws;                       // 6.4M halfs (12.8MB)
    _Float16* H16B   = H16A + (size_t)N_NODES * D;            // 6.4M halfs
    unsigned int* staged = (unsigned int*)d_ws;               // alias: 391*6144 u32
    int*      esrc   = (int*)(H16B + (size_t)N_NODES * D);    // 1.6M
    float*    dinv   = (float*)(esrc + N_EDGES);              // 100k
    int*      base   = (int*)(dinv + N_NODES);                // 100k+1 (+pad)
    float*    pooled = (float*)(base + N_NODES + 4);          // 32768
    float*    counts = pooled + N_GRAPHS * D;                 // 512
    int*      gcur   = (int*)(counts + N_GRAPHS);             // 391 (+pad to 512)
    int*      bstart = gcur + 512;                            // 392 (+pad to 512)
    _Float16* WhA    = (_Float16*)(bstart + 512);             // 4096 halfs (8KB)
    _Float16* WhB    = WhA + 4096;                            // 4096 halfs (8KB)

    // ---- fused setup: W2/W3 fp16 prep + cursor/pool zeroing (one launch) ----
    k_setup<<<132, 256, 0, stream>>>(W2, W3, WhA, WhB, gcur, pooled);

    // ---- CSR build: slab-bucketed scatter with in-bucket degree counting ----
    k_binA<<<(N_EDGES + EPB - 1) / EPB, 1024, 0, stream>>>(src, dst, gcur, staged);
    k_scanB<<<1, 512, 0, stream>>>(gcur, bstart);
    k_binB<<<NBUCK, 256, 0, stream>>>(staged, gcur, bstart, esrc, base, dinv);

    // ---- 3 GCN layers (mm1 separate; mm2/mm3 fused; pull3+pool fused) ----
    const int MMB = (N_NODES + 4 * MM_NPW - 1) / (4 * MM_NPW);  // 1563
    const int PB  = N_NODES / (4 * NPN);                        // 6250
    k_mm<<<MMB, 256, 0, stream>>>(x, W1, dinv, H16A);
    k_pullmm<<<PB, 256, 0, stream>>>(H16A, esrc, base, dinv, b1, WhA, H16B);
    k_pullmm<<<PB, 256, 0, stream>>>(H16B, esrc, base, dinv, b2, WhB, H16A);
    k_pull<<<PB, 256, 0, stream>>>(H16A, esrc, base, dinv, b3, seg, pooled, counts);

    // ---- head ----
    k_out<<<N_GRAPHS, 128, 0, stream>>>(pooled, counts, Wout, bout, out);
}

// Round 17
// 301.026 us; speedup vs baseline: 1.0572x; 1.0123x over previous
//
#include <hip/hip_runtime.h>

#define N_NODES   100000
#define N_EDGES   1600000
#define D         64
#define N_TARGETS 100
#define N_GRAPHS  512
#define NBUCK     391     // ceil(N_NODES / 256): bucket b = dst >> 8
#define EPB       16384   // edges per block in pass A (1024 thr x 16)
#define BCAP      6144    // bucket slab capacity (Poisson(4096) + 32 sigma)
#define MM_NPW    16      // nodes per wave in k_mm
#define NPN       4       // nodes per wave in pull kernels

typedef _Float16 half4 __attribute__((ext_vector_type(4)));
typedef _Float16 half8 __attribute__((ext_vector_type(8)));
typedef __fp16   hf2   __attribute__((ext_vector_type(2)));   // builtin-compatible
typedef __fp16   hf8   __attribute__((ext_vector_type(8)));

#if defined(__has_builtin)
#if __has_builtin(__builtin_amdgcn_fdot2)
#define USE_DOT2 1
#endif
#endif

// ---- fused setup: blk0/1 -> W2/W3 fp16 prep; blk2..131 -> zero gcur+pooled;
// blk132/133 -> counts[g] via binary search over sorted seg (static data!).
__device__ __forceinline__ void prepW_dev(const float* __restrict__ W,
                                          _Float16* __restrict__ out, int t) {
#pragma unroll
    for (int it = 0; it < 2; ++it) {
        int idx = t + it * 256;        // 512 (m, c) chunks
        int m = idx >> 3, c = idx & 7;
        half8 hv;
#pragma unroll
        for (int tt = 0; tt < 8; ++tt)
            hv[tt] = (_Float16)W[(8 * c + tt) * 64 + m];
        *(half8*)&out[m * 64 + ((c ^ (m & 7)) * 8)] = hv;
    }
}

__global__ void k_setup(const float* __restrict__ W2, const float* __restrict__ W3,
                        _Float16* __restrict__ WhA, _Float16* __restrict__ WhB,
                        int* __restrict__ gcur, float* __restrict__ poolz,
                        const int* __restrict__ seg, float* __restrict__ counts) {
    int blk = blockIdx.x;
    int t = threadIdx.x;
    if (blk == 0) { prepW_dev(W2, WhA, t); return; }
    if (blk == 1) { prepW_dev(W3, WhB, t); return; }
    if (blk >= 132) {   // counts via two binary searches (seg sorted)
        int gq = (blk - 132) * 256 + t;
        if (gq < N_GRAPHS) {
            int lo = 0, hi = N_NODES;
            while (lo < hi) { int mid = (lo + hi) >> 1; if (seg[mid] < gq) lo = mid + 1; else hi = mid; }
            int start = lo;
            hi = N_NODES;
            while (lo < hi) { int mid = (lo + hi) >> 1; if (seg[mid] <= gq) lo = mid + 1; else hi = mid; }
            counts[gq] = (float)(lo - start);
        }
        return;
    }
    int i = (blk - 2) * 256 + t;
    if (i < NBUCK) gcur[i] = 0;
    if (i < N_GRAPHS * D) poolz[i] = 0.0f;
}

// ---- pass A: bucket edges by dst>>8 into fixed-capacity slabs (u32-packed) ----
__global__ void __launch_bounds__(1024)
k_binA(const int* __restrict__ src, const int* __restrict__ dst,
       int* __restrict__ gcur, unsigned int* __restrict__ staged) {
    __shared__ int hist[NBUCK];
    __shared__ int boff[NBUCK];
    int tid = threadIdx.x;
    for (int i = tid; i < NBUCK; i += 1024) hist[i] = 0;
    __syncthreads();

    int e0 = blockIdx.x * EPB;
    int s_[16], d_[16], r_[16];
#pragma unroll
    for (int k = 0; k < 16; ++k) {
        int e = e0 + k * 1024 + tid;
        if (e < N_EDGES) {
            s_[k] = src[e];
            d_[k] = dst[e];
            r_[k] = atomicAdd(&hist[d_[k] >> 8], 1);
        } else {
            d_[k] = -1;
        }
    }
    __syncthreads();
    for (int b = tid; b < NBUCK; b += 1024) {
        int h = hist[b];
        boff[b] = (h > 0) ? atomicAdd(&gcur[b], h) : 0;
    }
    __syncthreads();
#pragma unroll
    for (int k = 0; k < 16; ++k) {
        if (d_[k] >= 0) {
            int b = d_[k] >> 8;
            staged[(size_t)b * BCAP + boff[b] + r_[k]] =
                ((unsigned)(d_[k] & 255) << 17) | (unsigned)s_[k];
        }
    }
}

// ---- scan bucket totals -> bucket edge-space starts ----
__global__ void k_scanB(const int* __restrict__ gcur, int* __restrict__ bstart) {
    __shared__ int s[512];
    int t = threadIdx.x;
    int v = (t < NBUCK) ? gcur[t] : 0;
    s[t] = v;
    __syncthreads();
    for (int off = 1; off < 512; off <<= 1) {
        int x = (t >= off) ? s[t - off] : 0;
        __syncthreads();
        s[t] += x;
        __syncthreads();
    }
    if (t < NBUCK) bstart[t] = s[t] - v;
    if (t == 0) bstart[NBUCK] = N_EDGES;
}

// ---- pass B: one block per bucket; LDS degree count + scan + place ----
__global__ void __launch_bounds__(256)
k_binB(const unsigned int* __restrict__ staged, const int* __restrict__ gcur,
       const int* __restrict__ bstart, int* __restrict__ esrc,
       int* __restrict__ base, float* __restrict__ dinv) {
    __shared__ int s[256];
    __shared__ int lbase[256];
    __shared__ int cur[256];
    int b = blockIdx.x;
    int t = threadIdx.x;
    int n0 = b << 8;
    int Eb = gcur[b];
    int Sb = bstart[b];
    const unsigned int* sl = staged + (size_t)b * BCAP;

    cur[t] = 0;
    __syncthreads();
    for (int k = t; k < Eb; k += 256) {
        int dl = (int)(sl[k] >> 17) & 255;
        atomicAdd(&cur[dl], 1);
    }
    __syncthreads();
    int v = cur[t];
    s[t] = v;
    __syncthreads();
    for (int off = 1; off < 256; off <<= 1) {
        int x = (t >= off) ? s[t - off] : 0;
        __syncthreads();
        s[t] += x;
        __syncthreads();
    }
    lbase[t] = s[t] - v;
    int gi = n0 + t;
    if (gi < N_NODES) {
        base[gi] = Sb + (s[t] - v);
        dinv[gi] = rsqrtf((float)v + 1.0f);   // +1 self-loop
    }
    if (b == 0 && t == 0) base[N_NODES] = N_EDGES;
    cur[t] = 0;
    __syncthreads();
    for (int k = t; k < Eb; k += 256) {
        unsigned int pd = sl[k];
        int dl = (int)(pd >> 17) & 255;
        int pos = Sb + lbase[dl] + atomicAdd(&cur[dl], 1);
        esrc[pos] = (int)(pd & 0x1FFFFu);
    }
}

// ------ matmul (layer 1): per-lane-feature, W1 column in registers ----------
__global__ void __launch_bounds__(256)
k_mm(const float* __restrict__ X, const float* __restrict__ W,
     const float* __restrict__ dinv, _Float16* __restrict__ Y16) {
    __shared__ float W1L[D * D];   // 16 KB raw [k][m]
    __shared__ float aSh[4][D];    // per-wave X row
    int tid = threadIdx.x;
#pragma unroll
    for (int it = 0; it < 4; ++it) {
        int idx = (tid + it * 256) * 4;
        *(float4*)&W1L[idx] = *(const float4*)(W + idx);
    }
    __syncthreads();

    int wv = tid >> 6, lane = tid & 63;
    float wreg[D];   // W1[k][lane] for all k
#pragma unroll
    for (int k = 0; k < D; ++k)
        wreg[k] = W1L[k * D + lane];

    int i0 = (blockIdx.x * 4 + wv) * MM_NPW;
    if (i0 >= N_NODES) return;
    int iEnd = i0 + MM_NPW; if (iEnd > N_NODES) iEnd = N_NODES;

    float xv = X[(size_t)i0 * D + lane];
    for (int i = i0; i < iEnd; ++i) {
        int inext = (i + 1 < N_NODES) ? (i + 1) : i;
        float xnext = X[(size_t)inext * D + lane];

        aSh[wv][lane] = xv;
        asm volatile("s_waitcnt lgkmcnt(0)" ::: "memory");

        float ac0 = 0.f, ac1 = 0.f, ac2 = 0.f, ac3 = 0.f;
#pragma unroll
        for (int c = 0; c < 16; ++c) {
            float4 a4 = *(const float4*)&aSh[wv][c * 4];
            ac0 = fmaf(a4.x, wreg[4 * c + 0], ac0);
            ac1 = fmaf(a4.y, wreg[4 * c + 1], ac1);
            ac2 = fmaf(a4.z, wreg[4 * c + 2], ac2);
            ac3 = fmaf(a4.w, wreg[4 * c + 3], ac3);
        }
        float acc = (ac0 + ac1) + (ac2 + ac3);
        Y16[(size_t)i * D + lane] = (_Float16)(acc * dinv[i]);
        xv = xnext;
    }
}

// ---- fused pull + matmul: R12 structure (NPN=4, no setup-prefetch) ----
__global__ void __launch_bounds__(256)
k_pullmm(const _Float16* __restrict__ H, const int* __restrict__ esrc,
         const int* __restrict__ base, const float* __restrict__ dinv,
         const float* __restrict__ b_in, const _Float16* __restrict__ Whg,
         _Float16* __restrict__ Hout) {
    __shared__ _Float16 WhL[D * D];        // 8KB swizzled Wt
    __shared__ float    red[4][8][D + 4];  // 8.5KB transpose-reduce tile
    __shared__ _Float16 aSh[4][D];         // 512B activation rows
    {
#pragma unroll
        for (int it = 0; it < 2; ++it) {
            int t = threadIdx.x + it * 256;
            *(half8*)&WhL[t * 8] = *(const half8*)&Whg[t * 8];
        }
    }
    __syncthreads();

    int wv   = threadIdx.x >> 6;
    int lane = threadIdx.x & 63;
    int g = lane >> 3, l = lane & 7;
    float bias = b_in[lane];
    int i0 = (blockIdx.x * 4 + wv) * NPN;

    for (int n = 0; n < NPN; ++n) {
        int i = i0 + n;
        int s0 = base[i], s1 = base[i + 1];

        float acc[8] = {0.f, 0.f, 0.f, 0.f, 0.f, 0.f, 0.f, 0.f};
        if (g == 0) {       // self contribution (group 0 only)
            half8 sv = *(const half8*)(H + (size_t)i * D + l * 8);
#pragma unroll
            for (int q = 0; q < 8; ++q) acc[q] = (float)sv[q];
        }

        int p = s0;
        while (p < s1) {
            int cnt = s1 - p;
            if (cnt > 64) cnt = 64;
            int ed = (lane < cnt) ? esrc[p + lane] : 0;
            int j = 0;
            for (; j + 32 <= cnt; j += 32) {
                int e0 = __shfl(ed, j + g, 64);
                int e1 = __shfl(ed, j + 8 + g, 64);
                int e2 = __shfl(ed, j + 16 + g, 64);
                int e3 = __shfl(ed, j + 24 + g, 64);
                half8 v0 = *(const half8*)(H + (size_t)(unsigned)e0 * D + l * 8);
                half8 v1 = *(const half8*)(H + (size_t)(unsigned)e1 * D + l * 8);
                half8 v2 = *(const half8*)(H + (size_t)(unsigned)e2 * D + l * 8);
                half8 v3 = *(const half8*)(H + (size_t)(unsigned)e3 * D + l * 8);
                half8 s01 = v0 + v1;
                half8 s23 = v2 + v3;
#pragma unroll
                for (int q = 0; q < 8; ++q)
                    acc[q] += (float)s01[q] + (float)s23[q];
            }
            for (; j + 16 <= cnt; j += 16) {
                int e0 = __shfl(ed, j + g, 64);
                int e1 = __shfl(ed, j + 8 + g, 64);
                half8 v0 = *(const half8*)(H + (size_t)(unsigned)e0 * D + l * 8);
                half8 v1 = *(const half8*)(H + (size_t)(unsigned)e1 * D + l * 8);
                half8 s01 = v0 + v1;
#pragma unroll
                for (int q = 0; q < 8; ++q) acc[q] += (float)s01[q];
            }
            for (; j + 8 <= cnt; j += 8) {
                int e0 = __shfl(ed, j + g, 64);
                half8 v0 = *(const half8*)(H + (size_t)(unsigned)e0 * D + l * 8);
#pragma unroll
                for (int q = 0; q < 8; ++q) acc[q] += (float)v0[q];
            }
            if (j < cnt) {
                int idx = j + g;
                int e0 = __shfl(ed, idx & 63, 64);
                if (idx < cnt) {
                    half8 v0 = *(const half8*)(H + (size_t)(unsigned)e0 * D + l * 8);
#pragma unroll
                    for (int q = 0; q < 8; ++q) acc[q] += (float)v0[q];
                }
            }
            p += cnt;
        }

        // ---- LDS transpose-reduce (2 independent add chains) ----
        *(float4*)&red[wv][g][l * 8]     = make_float4(acc[0], acc[1], acc[2], acc[3]);
        *(float4*)&red[wv][g][l * 8 + 4] = make_float4(acc[4], acc[5], acc[6], acc[7]);
        asm volatile("s_waitcnt lgkmcnt(0)" ::: "memory");
        float ag0 = 0.f, ag1 = 0.f;
#pragma unroll
        for (int gg = 0; gg < 8; gg += 2) {
            ag0 += red[wv][gg][lane];
            ag1 += red[wv][gg + 1][lane];
        }
        float agg = ag0 + ag1;

        float di = dinv[i];
        float av = fmaxf(fmaf(agg, di, bias), 0.f);
        aSh[wv][lane] = (_Float16)av;
        asm volatile("s_waitcnt lgkmcnt(0)" ::: "memory");

        // ---- dot2 epilogue: 4 independent accumulators ----
        float p0 = 0.f, p1 = 0.f, p2 = 0.f, p3 = 0.f;
#pragma unroll
        for (int c = 0; c < 8; ++c) {
            hf8 a8 = *(const hf8*)&aSh[wv][c * 8];                           // broadcast
            hf8 w8 = *(const hf8*)&WhL[lane * 64 + ((c ^ (lane & 7)) * 8)];  // swizzled
#ifdef USE_DOT2
            hf2 a0; a0.x = a8[0]; a0.y = a8[1];
            hf2 a1; a1.x = a8[2]; a1.y = a8[3];
            hf2 a2; a2.x = a8[4]; a2.y = a8[5];
            hf2 a3; a3.x = a8[6]; a3.y = a8[7];
            hf2 w0; w0.x = w8[0]; w0.y = w8[1];
            hf2 w1; w1.x = w8[2]; w1.y = w8[3];
            hf2 w2; w2.x = w8[4]; w2.y = w8[5];
            hf2 w3; w3.x = w8[6]; w3.y = w8[7];
            p0 = __builtin_amdgcn_fdot2(a0, w0, p0, false);
            p1 = __builtin_amdgcn_fdot2(a1, w1, p1, false);
            p2 = __builtin_amdgcn_fdot2(a2, w2, p2, false);
            p3 = __builtin_amdgcn_fdot2(a3, w3, p3, false);
#else
#pragma unroll
            for (int t = 0; t < 8; t += 4) {
                p0 = fmaf((float)a8[t],     (float)w8[t],     p0);
                p1 = fmaf((float)a8[t + 1], (float)w8[t + 1], p1);
                p2 = fmaf((float)a8[t + 2], (float)w8[t + 2], p2);
                p3 = fmaf((float)a8[t + 3], (float)w8[t + 3], p3);
            }
#endif
        }
        float part = (p0 + p1) + (p2 + p3);
        Hout[(size_t)i * D + lane] = (_Float16)(part * di);
    }
}

// ---- final pull (layer 3) + two-level fused mean-pool (R15 structure).
// R16 trim: run-merged register accumulation (seg sorted -> a wave's 4 nodes
// span 1-2 graphs) cuts LDS atomic batches ~4x; counts moved to k_setup
// (static data); used[] flags skip empty-slot flushes.
__global__ void __launch_bounds__(256)
k_pull(const _Float16* __restrict__ H, const int* __restrict__ esrc,
       const int* __restrict__ base, const float* __restrict__ dinv,
       const float* __restrict__ b, const int* __restrict__ seg,
       float* __restrict__ pooled) {
    __shared__ float red[4][8][D + 4];
    __shared__ float poolL[16][D];   // 4KB block-local pool
    __shared__ int   usedL[16];
    int wv   = threadIdx.x >> 6;
    int lane = threadIdx.x & 63;
    int g = lane >> 3, l = lane & 7;
    float bias = b[lane];
    int ib0 = blockIdx.x * 16;          // block's first node
    int g0  = seg[ib0];                 // block's first graph (seg sorted)
    int i0 = ib0 + wv * NPN;

    {   // zero the block pool
        int t = threadIdx.x;
#pragma unroll
        for (int z = 0; z < 4; ++z) poolL[(t * 4 + z) >> 6][(t * 4 + z) & 63] = 0.f;
        if (t < 16) usedL[t] = 0;
    }
    __syncthreads();

    int   curs = seg[i0];   // current run's graph (wave-uniform)
    float pacc = 0.f;       // run accumulator (per-lane feature)

    for (int n = 0; n < NPN; ++n) {
        int i = i0 + n;
        int s0 = base[i], s1 = base[i + 1];

        float acc[8] = {0.f, 0.f, 0.f, 0.f, 0.f, 0.f, 0.f, 0.f};
        if (g == 0) {
            half8 sv = *(const half8*)(H + (size_t)i * D + l * 8);
#pragma unroll
            for (int q = 0; q < 8; ++q) acc[q] = (float)sv[q];
        }

        int p = s0;
        while (p < s1) {
            int cnt = s1 - p;
            if (cnt > 64) cnt = 64;
            int ed = (lane < cnt) ? esrc[p + lane] : 0;
            int j = 0;
            for (; j + 32 <= cnt; j += 32) {
                int e0 = __shfl(ed, j + g, 64);
                int e1 = __shfl(ed, j + 8 + g, 64);
                int e2 = __shfl(ed, j + 16 + g, 64);
                int e3 = __shfl(ed, j + 24 + g, 64);
                half8 v0 = *(const half8*)(H + (size_t)(unsigned)e0 * D + l * 8);
                half8 v1 = *(const half8*)(H + (size_t)(unsigned)e1 * D + l * 8);
                half8 v2 = *(const half8*)(H + (size_t)(unsigned)e2 * D + l * 8);
                half8 v3 = *(const half8*)(H + (size_t)(unsigned)e3 * D + l * 8);
                half8 s01 = v0 + v1;
                half8 s23 = v2 + v3;
#pragma unroll
                for (int q = 0; q < 8; ++q)
                    acc[q] += (float)s01[q] + (float)s23[q];
            }
            for (; j + 16 <= cnt; j += 16) {
                int e0 = __shfl(ed, j + g, 64);
                int e1 = __shfl(ed, j + 8 + g, 64);
                half8 v0 = *(const half8*)(H + (size_t)(unsigned)e0 * D + l * 8);
                half8 v1 = *(const half8*)(H + (size_t)(unsigned)e1 * D + l * 8);
                half8 s01 = v0 + v1;
#pragma unroll
                for (int q = 0; q < 8; ++q) acc[q] += (float)s01[q];
            }
            for (; j + 8 <= cnt; j += 8) {
                int e0 = __shfl(ed, j + g, 64);
                half8 v0 = *(const half8*)(H + (size_t)(unsigned)e0 * D + l * 8);
#pragma unroll
                for (int q = 0; q < 8; ++q) acc[q] += (float)v0[q];
            }
            if (j < cnt) {
                int idx = j + g;
                int e0 = __shfl(ed, idx & 63, 64);
                if (idx < cnt) {
                    half8 v0 = *(const half8*)(H + (size_t)(unsigned)e0 * D + l * 8);
#pragma unroll
                    for (int q = 0; q < 8; ++q) acc[q] += (float)v0[q];
                }
            }
            p += cnt;
        }

        *(float4*)&red[wv][g][l * 8]     = make_float4(acc[0], acc[1], acc[2], acc[3]);
        *(float4*)&red[wv][g][l * 8 + 4] = make_float4(acc[4], acc[5], acc[6], acc[7]);
        asm volatile("s_waitcnt lgkmcnt(0)" ::: "memory");
        float ag0 = 0.f, ag1 = 0.f;
#pragma unroll
        for (int gg = 0; gg < 8; gg += 2) {
            ag0 += red[wv][gg][lane];
            ag1 += red[wv][gg + 1][lane];
        }
        float agg = ag0 + ag1;
        asm volatile("s_waitcnt lgkmcnt(0)" ::: "memory");

        float val = fmaf(agg, dinv[i], bias);   // fp32, no fp16 rounding

        int sg = seg[i];                        // wave-uniform
        if (sg != curs) {                       // flush previous run
            int slot = curs - g0;
            atomicAdd(&poolL[slot][lane], pacc);
            if (lane == 0) usedL[slot] = 1;
            pacc = 0.f;
            curs = sg;
        }
        pacc += val;
    }
    {   // flush final run
        int slot = curs - g0;
        atomicAdd(&poolL[slot][lane], pacc);
        if (lane == 0) usedL[slot] = 1;
    }
    __syncthreads();

    // block flush: wave wv handles slots wv, wv+4, wv+8, wv+12
#pragma unroll
    for (int k = 0; k < 4; ++k) {
        int slot = wv + 4 * k;
        if (usedL[slot]) {
            atomicAdd(&pooled[(size_t)(g0 + slot) * D + lane], poolL[slot][lane]);
        }
    }
}

// ---------------- head ----------------
__global__ void k_out(const float* __restrict__ pooled, const float* __restrict__ counts,
                      const float* __restrict__ Wout, const float* __restrict__ bout,
                      float* __restrict__ out) {
    __shared__ float prow[D];
    int g = blockIdx.x;
    int t = threadIdx.x;
    if (t < D) prow[t] = pooled[(size_t)g * D + t] / fmaxf(counts[g], 1.0f);
    __syncthreads();
    if (t < N_TARGETS) {
        float acc = bout[t];
#pragma unroll
        for (int k = 0; k < D; ++k)
            acc = fmaf(prow[k], Wout[k * N_TARGETS + t], acc);
        out[g * N_TARGETS + t] = acc;
    }
}

// ---------------- driver ----------------

extern "C" void kernel_launch(void* const* d_in, const int* in_sizes, int n_in,
                              void* d_out, int out_size, void* d_ws, size_t ws_size,
                              hipStream_t stream) {
    const float* x    = (const float*)d_in[0];
    const float* W1   = (const float*)d_in[1];
    const float* b1   = (const float*)d_in[2];
    const float* W2   = (const float*)d_in[3];
    const float* b2   = (const float*)d_in[4];
    const float* W3   = (const float*)d_in[5];
    const float* b3   = (const float*)d_in[6];
    const float* Wout = (const float*)d_in[7];
    const float* bout = (const float*)d_in[8];
    const int*   eidx = (const int*)d_in[9];
    const int*   seg  = (const int*)d_in[10];
    const int* src = eidx;
    const int* dst = eidx + N_EDGES;
    float* out = (float*)d_out;

    // workspace layout (~33 MB). staged (9.6 MB u32) aliases H16A (dead
    // during CSR build).
    _Float16* H16A   = (_Float16*)d_ws;                       // 6.4M halfs (12.8MB)
    _Float16* H16B   = H16A + (size_t)N_NODES * D;            // 6.4M halfs
    unsigned int* staged = (unsigned int*)d_ws;               // alias: 391*6144 u32
    int*      esrc   = (int*)(H16B + (size_t)N_NODES * D);    // 1.6M
    float*    dinv   = (float*)(esrc + N_EDGES);              // 100k
    int*      base   = (int*)(dinv + N_NODES);                // 100k+1 (+pad)
    float*    pooled = (float*)(base + N_NODES + 4);          // 32768
    float*    counts = pooled + N_GRAPHS * D;                 // 512
    int*      gcur   = (int*)(counts + N_GRAPHS);             // 391 (+pad to 512)
    int*      bstart = gcur + 512;                            // 392 (+pad to 512)
    _Float16* WhA    = (_Float16*)(bstart + 512);             // 4096 halfs (8KB)
    _Float16* WhB    = WhA + 4096;                            // 4096 halfs (8KB)

    // ---- fused setup: W prep + zeroing + static counts (one launch) ----
    k_setup<<<134, 256, 0, stream>>>(W2, W3, WhA, WhB, gcur, pooled, seg, counts);

    // ---- CSR build: slab-bucketed scatter with in-bucket degree counting ----
    k_binA<<<(N_EDGES + EPB - 1) / EPB, 1024, 0, stream>>>(src, dst, gcur, staged);
    k_scanB<<<1, 512, 0, stream>>>(gcur, bstart);
    k_binB<<<NBUCK, 256, 0, stream>>>(staged, gcur, bstart, esrc, base, dinv);

    // ---- 3 GCN layers (mm1 separate; mm2/mm3 fused; pull3+pool fused) ----
    const int MMB = (N_NODES + 4 * MM_NPW - 1) / (4 * MM_NPW);  // 1563
    const int PB  = N_NODES / (4 * NPN);                        // 6250
    k_mm<<<MMB, 256, 0, stream>>>(x, W1, dinv, H16A);
    k_pullmm<<<PB, 256, 0, stream>>>(H16A, esrc, base, dinv, b1, WhA, H16B);
    k_pullmm<<<PB, 256, 0, stream>>>(H16B, esrc, base, dinv, b2, WhB, H16A);
    k_pull<<<PB, 256, 0, stream>>>(H16A, esrc, base, dinv, b3, seg, pooled);

    // ---- head ----
    k_out<<<N_GRAPHS, 128, 0, stream>>>(pooled, counts, Wout, bout, out);
}

// Round 18
// 297.689 us; speedup vs baseline: 1.0691x; 1.0112x over previous
//
#include <hip/hip_runtime.h>

#define N_NODES   100000
#define N_EDGES   1600000
#define D         64
#define N_TARGETS 100
#define N_GRAPHS  512
#define NBUCK     391     // ceil(N_NODES / 256): bucket b = dst >> 8
#define EPB       16384   // edges per block in pass A (1024 thr x 16)
#define BCAP      6144    // bucket slab capacity (Poisson(4096) + 32 sigma)
#define MM_NPW    16      // nodes per wave in k_mm
#define NPN       4       // nodes per wave in pull kernels

typedef _Float16 half4 __attribute__((ext_vector_type(4)));
typedef _Float16 half8 __attribute__((ext_vector_type(8)));
typedef __fp16   hf2   __attribute__((ext_vector_type(2)));   // builtin-compatible
typedef __fp16   hf8   __attribute__((ext_vector_type(8)));

#if defined(__has_builtin)
#if __has_builtin(__builtin_amdgcn_fdot2)
#define USE_DOT2 1
#endif
#endif

// ---- fused setup: blk0/1 -> W2/W3 fp16 prep; blk2..131 -> zero gcur+pooled;
// blk132/133 -> counts[g] via binary search over sorted seg (static data).
__device__ __forceinline__ void prepW_dev(const float* __restrict__ W,
                                          _Float16* __restrict__ out, int t) {
#pragma unroll
    for (int it = 0; it < 2; ++it) {
        int idx = t + it * 256;        // 512 (m, c) chunks
        int m = idx >> 3, c = idx & 7;
        half8 hv;
#pragma unroll
        for (int tt = 0; tt < 8; ++tt)
            hv[tt] = (_Float16)W[(8 * c + tt) * 64 + m];
        *(half8*)&out[m * 64 + ((c ^ (m & 7)) * 8)] = hv;
    }
}

__global__ void k_setup(const float* __restrict__ W2, const float* __restrict__ W3,
                        _Float16* __restrict__ WhA, _Float16* __restrict__ WhB,
                        int* __restrict__ gcur, float* __restrict__ poolz,
                        const int* __restrict__ seg, float* __restrict__ counts) {
    int blk = blockIdx.x;
    int t = threadIdx.x;
    if (blk == 0) { prepW_dev(W2, WhA, t); return; }
    if (blk == 1) { prepW_dev(W3, WhB, t); return; }
    if (blk >= 132) {   // counts via two binary searches (seg sorted)
        int gq = (blk - 132) * 256 + t;
        if (gq < N_GRAPHS) {
            int lo = 0, hi = N_NODES;
            while (lo < hi) { int mid = (lo + hi) >> 1; if (seg[mid] < gq) lo = mid + 1; else hi = mid; }
            int start = lo;
            hi = N_NODES;
            while (lo < hi) { int mid = (lo + hi) >> 1; if (seg[mid] <= gq) lo = mid + 1; else hi = mid; }
            counts[gq] = (float)(lo - start);
        }
        return;
    }
    int i = (blk - 2) * 256 + t;
    if (i < NBUCK) gcur[i] = 0;
    if (i < N_GRAPHS * D) poolz[i] = 0.0f;
}

// ---- pass A: bucket edges by dst>>8 into fixed-capacity slabs (u32-packed) ----
__global__ void __launch_bounds__(1024)
k_binA(const int* __restrict__ src, const int* __restrict__ dst,
       int* __restrict__ gcur, unsigned int* __restrict__ staged) {
    __shared__ int hist[NBUCK];
    __shared__ int boff[NBUCK];
    int tid = threadIdx.x;
    for (int i = tid; i < NBUCK; i += 1024) hist[i] = 0;
    __syncthreads();

    int e0 = blockIdx.x * EPB;
    int s_[16], d_[16], r_[16];
#pragma unroll
    for (int k = 0; k < 16; ++k) {
        int e = e0 + k * 1024 + tid;
        if (e < N_EDGES) {
            s_[k] = src[e];
            d_[k] = dst[e];
            r_[k] = atomicAdd(&hist[d_[k] >> 8], 1);
        } else {
            d_[k] = -1;
        }
    }
    __syncthreads();
    for (int b = tid; b < NBUCK; b += 1024) {
        int h = hist[b];
        boff[b] = (h > 0) ? atomicAdd(&gcur[b], h) : 0;
    }
    __syncthreads();
#pragma unroll
    for (int k = 0; k < 16; ++k) {
        if (d_[k] >= 0) {
            int b = d_[k] >> 8;
            staged[(size_t)b * BCAP + boff[b] + r_[k]] =
                ((unsigned)(d_[k] & 255) << 17) | (unsigned)s_[k];
        }
    }
}

// ---- pass B: one block per bucket; INLINE bucket-prefix (replaces k_scanB) +
// LDS degree count + scan + place. One fewer kernel/launch on the serial path.
__global__ void __launch_bounds__(256)
k_binB(const unsigned int* __restrict__ staged, const int* __restrict__ gcur,
       int* __restrict__ esrc, int* __restrict__ base, float* __restrict__ dinv) {
    __shared__ int s[256];
    __shared__ int lbase[256];
    __shared__ int cur[256];
    int b = blockIdx.x;
    int t = threadIdx.x;
    int n0 = b << 8;
    int Eb = gcur[b];

    // inline Sb = sum(gcur[0..b)) : strided partials + LDS scan (s[255]=total)
    int part = 0;
    for (int k = t; k < b; k += 256) part += gcur[k];
    s[t] = part;
    __syncthreads();
    for (int off = 1; off < 256; off <<= 1) {
        int x = (t >= off) ? s[t - off] : 0;
        __syncthreads();
        s[t] += x;
        __syncthreads();
    }
    int Sb = s[255];
    const unsigned int* sl = staged + (size_t)b * BCAP;

    cur[t] = 0;
    __syncthreads();
    for (int k = t; k < Eb; k += 256) {
        int dl = (int)(sl[k] >> 17) & 255;
        atomicAdd(&cur[dl], 1);
    }
    __syncthreads();
    int v = cur[t];
    s[t] = v;
    __syncthreads();
    for (int off = 1; off < 256; off <<= 1) {
        int x = (t >= off) ? s[t - off] : 0;
        __syncthreads();
        s[t] += x;
        __syncthreads();
    }
    lbase[t] = s[t] - v;
    int gi = n0 + t;
    if (gi < N_NODES) {
        base[gi] = Sb + (s[t] - v);
        dinv[gi] = rsqrtf((float)v + 1.0f);   // +1 self-loop
    }
    if (b == 0 && t == 0) base[N_NODES] = N_EDGES;
    cur[t] = 0;
    __syncthreads();
    for (int k = t; k < Eb; k += 256) {
        unsigned int pd = sl[k];
        int dl = (int)(pd >> 17) & 255;
        int pos = Sb + lbase[dl] + atomicAdd(&cur[dl], 1);
        esrc[pos] = (int)(pd & 0x1FFFFu);
    }
}

// ------ matmul (layer 1): per-lane-feature, W1 column in registers ----------
__global__ void __launch_bounds__(256)
k_mm(const float* __restrict__ X, const float* __restrict__ W,
     const float* __restrict__ dinv, _Float16* __restrict__ Y16) {
    __shared__ float W1L[D * D];   // 16 KB raw [k][m]
    __shared__ float aSh[4][D];    // per-wave X row
    int tid = threadIdx.x;
#pragma unroll
    for (int it = 0; it < 4; ++it) {
        int idx = (tid + it * 256) * 4;
        *(float4*)&W1L[idx] = *(const float4*)(W + idx);
    }
    __syncthreads();

    int wv = tid >> 6, lane = tid & 63;
    float wreg[D];   // W1[k][lane] for all k
#pragma unroll
    for (int k = 0; k < D; ++k)
        wreg[k] = W1L[k * D + lane];

    int i0 = (blockIdx.x * 4 + wv) * MM_NPW;
    if (i0 >= N_NODES) return;
    int iEnd = i0 + MM_NPW; if (iEnd > N_NODES) iEnd = N_NODES;

    float xv = X[(size_t)i0 * D + lane];
    for (int i = i0; i < iEnd; ++i) {
        int inext = (i + 1 < N_NODES) ? (i + 1) : i;
        float xnext = X[(size_t)inext * D + lane];

        aSh[wv][lane] = xv;
        asm volatile("s_waitcnt lgkmcnt(0)" ::: "memory");

        float ac0 = 0.f, ac1 = 0.f, ac2 = 0.f, ac3 = 0.f;
#pragma unroll
        for (int c = 0; c < 16; ++c) {
            float4 a4 = *(const float4*)&aSh[wv][c * 4];
            ac0 = fmaf(a4.x, wreg[4 * c + 0], ac0);
            ac1 = fmaf(a4.y, wreg[4 * c + 1], ac1);
            ac2 = fmaf(a4.z, wreg[4 * c + 2], ac2);
            ac3 = fmaf(a4.w, wreg[4 * c + 3], ac3);
        }
        float acc = (ac0 + ac1) + (ac2 + ac3);
        Y16[(size_t)i * D + lane] = (_Float16)(acc * dinv[i]);
        xv = xnext;
    }
}

// ---- fused pull + matmul: R12 structure (NPN=4, no setup-prefetch) ----
__global__ void __launch_bounds__(256)
k_pullmm(const _Float16* __restrict__ H, const int* __restrict__ esrc,
         const int* __restrict__ base, const float* __restrict__ dinv,
         const float* __restrict__ b_in, const _Float16* __restrict__ Whg,
         _Float16* __restrict__ Hout) {
    __shared__ _Float16 WhL[D * D];        // 8KB swizzled Wt
    __shared__ float    red[4][8][D + 4];  // 8.5KB transpose-reduce tile
    __shared__ _Float16 aSh[4][D];         // 512B activation rows
    {
#pragma unroll
        for (int it = 0; it < 2; ++it) {
            int t = threadIdx.x + it * 256;
            *(half8*)&WhL[t * 8] = *(const half8*)&Whg[t * 8];
        }
    }
    __syncthreads();

    int wv   = threadIdx.x >> 6;
    int lane = threadIdx.x & 63;
    int g = lane >> 3, l = lane & 7;
    float bias = b_in[lane];
    int i0 = (blockIdx.x * 4 + wv) * NPN;

    for (int n = 0; n < NPN; ++n) {
        int i = i0 + n;
        int s0 = base[i], s1 = base[i + 1];

        float acc[8] = {0.f, 0.f, 0.f, 0.f, 0.f, 0.f, 0.f, 0.f};
        if (g == 0) {       // self contribution (group 0 only)
            half8 sv = *(const half8*)(H + (size_t)i * D + l * 8);
#pragma unroll
            for (int q = 0; q < 8; ++q) acc[q] = (float)sv[q];
        }

        int p = s0;
        while (p < s1) {
            int cnt = s1 - p;
            if (cnt > 64) cnt = 64;
            int ed = (lane < cnt) ? esrc[p + lane] : 0;
            int j = 0;
            for (; j + 32 <= cnt; j += 32) {
                int e0 = __shfl(ed, j + g, 64);
                int e1 = __shfl(ed, j + 8 + g, 64);
                int e2 = __shfl(ed, j + 16 + g, 64);
                int e3 = __shfl(ed, j + 24 + g, 64);
                half8 v0 = *(const half8*)(H + (size_t)(unsigned)e0 * D + l * 8);
                half8 v1 = *(const half8*)(H + (size_t)(unsigned)e1 * D + l * 8);
                half8 v2 = *(const half8*)(H + (size_t)(unsigned)e2 * D + l * 8);
                half8 v3 = *(const half8*)(H + (size_t)(unsigned)e3 * D + l * 8);
                half8 s01 = v0 + v1;
                half8 s23 = v2 + v3;
#pragma unroll
                for (int q = 0; q < 8; ++q)
                    acc[q] += (float)s01[q] + (float)s23[q];
            }
            for (; j + 16 <= cnt; j += 16) {
                int e0 = __shfl(ed, j + g, 64);
                int e1 = __shfl(ed, j + 8 + g, 64);
                half8 v0 = *(const half8*)(H + (size_t)(unsigned)e0 * D + l * 8);
                half8 v1 = *(const half8*)(H + (size_t)(unsigned)e1 * D + l * 8);
                half8 s01 = v0 + v1;
#pragma unroll
                for (int q = 0; q < 8; ++q) acc[q] += (float)s01[q];
            }
            for (; j + 8 <= cnt; j += 8) {
                int e0 = __shfl(ed, j + g, 64);
                half8 v0 = *(const half8*)(H + (size_t)(unsigned)e0 * D + l * 8);
#pragma unroll
                for (int q = 0; q < 8; ++q) acc[q] += (float)v0[q];
            }
            if (j < cnt) {
                int idx = j + g;
                int e0 = __shfl(ed, idx & 63, 64);
                if (idx < cnt) {
                    half8 v0 = *(const half8*)(H + (size_t)(unsigned)e0 * D + l * 8);
#pragma unroll
                    for (int q = 0; q < 8; ++q) acc[q] += (float)v0[q];
                }
            }
            p += cnt;
        }

        // ---- LDS transpose-reduce (2 independent add chains) ----
        *(float4*)&red[wv][g][l * 8]     = make_float4(acc[0], acc[1], acc[2], acc[3]);
        *(float4*)&red[wv][g][l * 8 + 4] = make_float4(acc[4], acc[5], acc[6], acc[7]);
        asm volatile("s_waitcnt lgkmcnt(0)" ::: "memory");
        float ag0 = 0.f, ag1 = 0.f;
#pragma unroll
        for (int gg = 0; gg < 8; gg += 2) {
            ag0 += red[wv][gg][lane];
            ag1 += red[wv][gg + 1][lane];
        }
        float agg = ag0 + ag1;

        float di = dinv[i];
        float av = fmaxf(fmaf(agg, di, bias), 0.f);
        aSh[wv][lane] = (_Float16)av;
        asm volatile("s_waitcnt lgkmcnt(0)" ::: "memory");

        // ---- dot2 epilogue: 4 independent accumulators ----
        float p0 = 0.f, p1 = 0.f, p2 = 0.f, p3 = 0.f;
#pragma unroll
        for (int c = 0; c < 8; ++c) {
            hf8 a8 = *(const hf8*)&aSh[wv][c * 8];                           // broadcast
            hf8 w8 = *(const hf8*)&WhL[lane * 64 + ((c ^ (lane & 7)) * 8)];  // swizzled
#ifdef USE_DOT2
            hf2 a0; a0.x = a8[0]; a0.y = a8[1];
            hf2 a1; a1.x = a8[2]; a1.y = a8[3];
            hf2 a2; a2.x = a8[4]; a2.y = a8[5];
            hf2 a3; a3.x = a8[6]; a3.y = a8[7];
            hf2 w0; w0.x = w8[0]; w0.y = w8[1];
            hf2 w1; w1.x = w8[2]; w1.y = w8[3];
            hf2 w2; w2.x = w8[4]; w2.y = w8[5];
            hf2 w3; w3.x = w8[6]; w3.y = w8[7];
            p0 = __builtin_amdgcn_fdot2(a0, w0, p0, false);
            p1 = __builtin_amdgcn_fdot2(a1, w1, p1, false);
            p2 = __builtin_amdgcn_fdot2(a2, w2, p2, false);
            p3 = __builtin_amdgcn_fdot2(a3, w3, p3, false);
#else
#pragma unroll
            for (int t = 0; t < 8; t += 4) {
                p0 = fmaf((float)a8[t],     (float)w8[t],     p0);
                p1 = fmaf((float)a8[t + 1], (float)w8[t + 1], p1);
                p2 = fmaf((float)a8[t + 2], (float)w8[t + 2], p2);
                p3 = fmaf((float)a8[t + 3], (float)w8[t + 3], p3);
            }
#endif
        }
        float part = (p0 + p1) + (p2 + p3);
        Hout[(size_t)i * D + lane] = (_Float16)(part * di);
    }
}

// ---- final pull (layer 3) + two-level fused mean-pool (R16 structure) ----
__global__ void __launch_bounds__(256)
k_pull(const _Float16* __restrict__ H, const int* __restrict__ esrc,
       const int* __restrict__ base, const float* __restrict__ dinv,
       const float* __restrict__ b, const int* __restrict__ seg,
       float* __restrict__ pooled) {
    __shared__ float red[4][8][D + 4];
    __shared__ float poolL[16][D];   // 4KB block-local pool
    __shared__ int   usedL[16];
    int wv   = threadIdx.x >> 6;
    int lane = threadIdx.x & 63;
    int g = lane >> 3, l = lane & 7;
    float bias = b[lane];
    int ib0 = blockIdx.x * 16;          // block's first node
    int g0  = seg[ib0];                 // block's first graph (seg sorted)
    int i0 = ib0 + wv * NPN;

    {   // zero the block pool
        int t = threadIdx.x;
#pragma unroll
        for (int z = 0; z < 4; ++z) poolL[(t * 4 + z) >> 6][(t * 4 + z) & 63] = 0.f;
        if (t < 16) usedL[t] = 0;
    }
    __syncthreads();

    int   curs = seg[i0];   // current run's graph (wave-uniform)
    float pacc = 0.f;       // run accumulator (per-lane feature)

    for (int n = 0; n < NPN; ++n) {
        int i = i0 + n;
        int s0 = base[i], s1 = base[i + 1];

        float acc[8] = {0.f, 0.f, 0.f, 0.f, 0.f, 0.f, 0.f, 0.f};
        if (g == 0) {
            half8 sv = *(const half8*)(H + (size_t)i * D + l * 8);
#pragma unroll
            for (int q = 0; q < 8; ++q) acc[q] = (float)sv[q];
        }

        int p = s0;
        while (p < s1) {
            int cnt = s1 - p;
            if (cnt > 64) cnt = 64;
            int ed = (lane < cnt) ? esrc[p + lane] : 0;
            int j = 0;
            for (; j + 32 <= cnt; j += 32) {
                int e0 = __shfl(ed, j + g, 64);
                int e1 = __shfl(ed, j + 8 + g, 64);
                int e2 = __shfl(ed, j + 16 + g, 64);
                int e3 = __shfl(ed, j + 24 + g, 64);
                half8 v0 = *(const half8*)(H + (size_t)(unsigned)e0 * D + l * 8);
                half8 v1 = *(const half8*)(H + (size_t)(unsigned)e1 * D + l * 8);
                half8 v2 = *(const half8*)(H + (size_t)(unsigned)e2 * D + l * 8);
                half8 v3 = *(const half8*)(H + (size_t)(unsigned)e3 * D + l * 8);
                half8 s01 = v0 + v1;
                half8 s23 = v2 + v3;
#pragma unroll
                for (int q = 0; q < 8; ++q)
                    acc[q] += (float)s01[q] + (float)s23[q];
            }
            for (; j + 16 <= cnt; j += 16) {
                int e0 = __shfl(ed, j + g, 64);
                int e1 = __shfl(ed, j + 8 + g, 64);
                half8 v0 = *(const half8*)(H + (size_t)(unsigned)e0 * D + l * 8);
                half8 v1 = *(const half8*)(H + (size_t)(unsigned)e1 * D + l * 8);
                half8 s01 = v0 + v1;
#pragma unroll
                for (int q = 0; q < 8; ++q) acc[q] += (float)s01[q];
            }
            for (; j + 8 <= cnt; j += 8) {
                int e0 = __shfl(ed, j + g, 64);
                half8 v0 = *(const half8*)(H + (size_t)(unsigned)e0 * D + l * 8);
#pragma unroll
                for (int q = 0; q < 8; ++q) acc[q] += (float)v0[q];
            }
            if (j < cnt) {
                int idx = j + g;
                int e0 = __shfl(ed, idx & 63, 64);
                if (idx < cnt) {
                    half8 v0 = *(const half8*)(H + (size_t)(unsigned)e0 * D + l * 8);
#pragma unroll
                    for (int q = 0; q < 8; ++q) acc[q] += (float)v0[q];
                }
            }
            p += cnt;
        }

        *(float4*)&red[wv][g][l * 8]     = make_float4(acc[0], acc[1], acc[2], acc[3]);
        *(float4*)&red[wv][g][l * 8 + 4] = make_float4(acc[4], acc[5], acc[6], acc[7]);
        asm volatile("s_waitcnt lgkmcnt(0)" ::: "memory");
        float ag0 = 0.f, ag1 = 0.f;
#pragma unroll
        for (int gg = 0; gg < 8; gg += 2) {
            ag0 += red[wv][gg][lane];
            ag1 += red[wv][gg + 1][lane];
        }
        float agg = ag0 + ag1;
        asm volatile("s_waitcnt lgkmcnt(0)" ::: "memory");

        float val = fmaf(agg, dinv[i], bias);   // fp32, no fp16 rounding

        int sg = seg[i];                        // wave-uniform
        if (sg != curs) {                       // flush previous run
            int slot = curs - g0;
            atomicAdd(&poolL[slot][lane], pacc);
            if (lane == 0) usedL[slot] = 1;
            pacc = 0.f;
            curs = sg;
        }
        pacc += val;
    }
    {   // flush final run
        int slot = curs - g0;
        atomicAdd(&poolL[slot][lane], pacc);
        if (lane == 0) usedL[slot] = 1;
    }
    __syncthreads();

    // block flush: wave wv handles slots wv, wv+4, wv+8, wv+12
#pragma unroll
    for (int k = 0; k < 4; ++k) {
        int slot = wv + 4 * k;
        if (usedL[slot]) {
            atomicAdd(&pooled[(size_t)(g0 + slot) * D + lane], poolL[slot][lane]);
        }
    }
}

// ---------------- head ----------------
__global__ void k_out(const float* __restrict__ pooled, const float* __restrict__ counts,
                      const float* __restrict__ Wout, const float* __restrict__ bout,
                      float* __restrict__ out) {
    __shared__ float prow[D];
    int g = blockIdx.x;
    int t = threadIdx.x;
    if (t < D) prow[t] = pooled[(size_t)g * D + t] / fmaxf(counts[g], 1.0f);
    __syncthreads();
    if (t < N_TARGETS) {
        float acc = bout[t];
#pragma unroll
        for (int k = 0; k < D; ++k)
            acc = fmaf(prow[k], Wout[k * N_TARGETS + t], acc);
        out[g * N_TARGETS + t] = acc;
    }
}

// ---------------- driver ----------------

extern "C" void kernel_launch(void* const* d_in, const int* in_sizes, int n_in,
                              void* d_out, int out_size, void* d_ws, size_t ws_size,
                              hipStream_t stream) {
    const float* x    = (const float*)d_in[0];
    const float* W1   = (const float*)d_in[1];
    const float* b1   = (const float*)d_in[2];
    const float* W2   = (const float*)d_in[3];
    const float* b2   = (const float*)d_in[4];
    const float* W3   = (const float*)d_in[5];
    const float* b3   = (const float*)d_in[6];
    const float* Wout = (const float*)d_in[7];
    const float* bout = (const float*)d_in[8];
    const int*   eidx = (const int*)d_in[9];
    const int*   seg  = (const int*)d_in[10];
    const int* src = eidx;
    const int* dst = eidx + N_EDGES;
    float* out = (float*)d_out;

    // workspace layout (~33 MB). staged (9.6 MB u32) aliases H16A (dead
    // during CSR build).
    _Float16* H16A   = (_Float16*)d_ws;                       // 6.4M halfs (12.8MB)
    _Float16* H16B   = H16A + (size_t)N_NODES * D;            // 6.4M halfs
    unsigned int* staged = (unsigned int*)d_ws;               // alias: 391*6144 u32
    int*      esrc   = (int*)(H16B + (size_t)N_NODES * D);    // 1.6M
    float*    dinv   = (float*)(esrc + N_EDGES);              // 100k
    int*      base   = (int*)(dinv + N_NODES);                // 100k+1 (+pad)
    float*    pooled = (float*)(base + N_NODES + 4);          // 32768
    float*    counts = pooled + N_GRAPHS * D;                 // 512
    int*      gcur   = (int*)(counts + N_GRAPHS);             // 391 (+pad to 512)
    _Float16* WhA    = (_Float16*)(gcur + 512);               // 4096 halfs (8KB)
    _Float16* WhB    = WhA + 4096;                            // 4096 halfs (8KB)

    // ---- fused setup: W prep + zeroing + static counts (one launch) ----
    k_setup<<<134, 256, 0, stream>>>(W2, W3, WhA, WhB, gcur, pooled, seg, counts);

    // ---- CSR build: binA scatter; binB (inline bucket-prefix) count+place ----
    k_binA<<<(N_EDGES + EPB - 1) / EPB, 1024, 0, stream>>>(src, dst, gcur, staged);
    k_binB<<<NBUCK, 256, 0, stream>>>(staged, gcur, esrc, base, dinv);

    // ---- 3 GCN layers (mm1 separate; mm2/mm3 fused; pull3+pool fused) ----
    const int MMB = (N_NODES + 4 * MM_NPW - 1) / (4 * MM_NPW);  // 1563
    const int PB  = N_NODES / (4 * NPN);                        // 6250
    k_mm<<<MMB, 256, 0, stream>>>(x, W1, dinv, H16A);
    k_pullmm<<<PB, 256, 0, stream>>>(H16A, esrc, base, dinv, b1, WhA, H16B);
    k_pullmm<<<PB, 256, 0, stream>>>(H16B, esrc, base, dinv, b2, WhB, H16A);
    k_pull<<<PB, 256, 0, stream>>>(H16A, esrc, base, dinv, b3, seg, pooled);

    // ---- head ----
    k_out<<<N_GRAPHS, 128, 0, stream>>>(pooled, counts, Wout, bout, out);
}